// Round 7
// baseline (383.780 us; speedup 1.0000x reference)
//
#include <hip/hip_runtime.h>
#include <math.h>

// ---------------- problem constants ----------------
#define DIM_   1024
#define STATE_ 64
#define HEADS_ 8
#define INNER_ 2048
#define HDIM_  256          // INNER/HEADS
#define B_     2
#define L_     2048
#define M_     (B_*L_)      // 4096 rows total
#define EPS_   1e-5f
#define Q_     64           // SSD chunk length
#define NC_    (L_/Q_)      // 32 chunks per sequence
#define NCHUNK_ (B_*HEADS_*NC_)  // 512 chunk-blocks
#define BCS_   1024         // combined B|C projection row stride
#define XZS_   4096         // combined x|z row stride

typedef _Float16 f16;
typedef __attribute__((ext_vector_type(8))) _Float16 half8;
typedef __attribute__((ext_vector_type(4))) _Float16 half4;
typedef __attribute__((ext_vector_type(4))) float    f32x4;

__device__ __forceinline__ float siluf(float x) { return x / (1.f + expf(-x)); }

__device__ __forceinline__ void gload_lds16(const void* g, void* l) {
    __builtin_amdgcn_global_load_lds((const __attribute__((address_space(1))) void*)g,
                                     (__attribute__((address_space(3))) void*)l, 16, 0, 0);
}

// ---------------- merged fp32 -> f16 cast of all operands (incl. gn_w/gn_b) ----------------
__global__ __launch_bounds__(256) void cast_all(const float* __restrict__ in0,
                                                const float* __restrict__ Wx,
                                                const float* __restrict__ Wz,
                                                const float* __restrict__ Wb,
                                                const float* __restrict__ Wc,
                                                const float* __restrict__ Wout,
                                                const float* __restrict__ gw,
                                                const float* __restrict__ gb,
                                                f16* __restrict__ input_h,
                                                f16* __restrict__ wxz_h,
                                                f16* __restrict__ wbc_h,
                                                f16* __restrict__ wout_h,
                                                f16* __restrict__ gnw_h,
                                                f16* __restrict__ gnb_h) {
    int i = blockIdx.x * 256 + threadIdx.x;
    const float* src; f16* dst; int off;
    if      (i < 1048576) { src = in0;  dst = input_h;            off = i; }
    else if (i < 1572864) { src = Wx;   dst = wxz_h;              off = i - 1048576; }
    else if (i < 2097152) { src = Wz;   dst = wxz_h + 2097152;    off = i - 1572864; }
    else if (i < 2359296) { src = Wb;   dst = wbc_h;              off = i - 2097152; }
    else if (i < 2621440) { src = Wc;   dst = wbc_h + 1048576;    off = i - 2359296; }
    else if (i < 3145728) { src = Wout; dst = wout_h;             off = i - 2621440; }
    else if (i < 3146240) { src = gw;   dst = gnw_h;              off = i - 3145728; }
    else                  { src = gb;   dst = gnb_h;              off = i - 3146240; }
    float4 v = *(const float4*)&src[(size_t)off * 4];
    half4 o;
    o[0] = (f16)v.x; o[1] = (f16)v.y; o[2] = (f16)v.z; o[3] = (f16)v.w;
    *(half4*)&dst[(size_t)off * 4] = o;
}

// ---------------- f16 MFMA GEMM: C[M x N] = A[M x K] * W[N x K]^T ----------------
// SILUZ: apply silu() to output columns >= INNER_ (the z half of the xz projection).
template<int BN, bool OUTF16, bool SILUZ>
__global__ __launch_bounds__(256) void hgemm(const f16* __restrict__ A,
                                             const f16* __restrict__ W,
                                             void* __restrict__ Cout,
                                             int K, int N) {
    constexpr int N_FR = BN / 32;            // per-wave n fragments
    constexpr int NITER = (128 + BN) / 64;   // staging issues per thread
    __shared__ f16 sA[128 * 32];
    __shared__ f16 sW[BN * 32];
    const int tid  = threadIdx.x;
    const int wid  = tid >> 6;
    const int lane = tid & 63;
    const int bm = blockIdx.y * 128;
    const int bn = blockIdx.x * BN;
    const int wr = wid >> 1, wc = wid & 1;
    const int r  = lane & 15, kg = lane >> 4;

    const f16* gsrc[NITER];
    f16* ldst[NITER];
#pragma unroll
    for (int i = 0; i < NITER; ++i) {
        int slot = tid + i * 256;
        if (slot < 512) {
            int row = slot >> 2;
            int kgv = ((slot & 3) ^ ((row >> 1) & 3)) * 8;
            gsrc[i] = A + (size_t)(bm + row) * K + kgv;
        } else {
            int row = (slot - 512) >> 2;
            int kgv = ((slot & 3) ^ ((row >> 1) & 3)) * 8;
            gsrc[i] = W + (size_t)(bn + row) * K + kgv;
        }
        int slot0 = (tid & ~63) + i * 256;   // wave-uniform base slot
        ldst[i] = (slot0 < 512) ? &sA[slot0 * 8] : &sW[(slot0 - 512) * 8];
    }

    int aoff[4], boff[N_FR];
#pragma unroll
    for (int m = 0; m < 4; ++m) {
        int arow = wr * 64 + m * 16 + r;
        aoff[m] = arow * 32 + ((kg ^ ((arow >> 1) & 3)) << 3);
    }
#pragma unroll
    for (int n = 0; n < N_FR; ++n) {
        int wrow = wc * (BN / 2) + n * 16 + r;
        boff[n] = wrow * 32 + ((kg ^ ((wrow >> 1) & 3)) << 3);
    }

    f32x4 acc[4][N_FR];
#pragma unroll
    for (int m = 0; m < 4; ++m)
#pragma unroll
        for (int n = 0; n < N_FR; ++n) acc[m][n] = (f32x4)0.f;

    for (int k0 = 0; k0 < K; k0 += 32) {
#pragma unroll
        for (int i = 0; i < NITER; ++i) gload_lds16(gsrc[i] + k0, ldst[i]);
        __syncthreads();
        half8 av[4], bv[N_FR];
#pragma unroll
        for (int m = 0; m < 4; ++m) av[m] = *(const half8*)&sA[aoff[m]];
#pragma unroll
        for (int n = 0; n < N_FR; ++n) bv[n] = *(const half8*)&sW[boff[n]];
#pragma unroll
        for (int m = 0; m < 4; ++m)
#pragma unroll
            for (int n = 0; n < N_FR; ++n)
                acc[m][n] = __builtin_amdgcn_mfma_f32_16x16x32_f16(av[m], bv[n], acc[m][n], 0, 0, 0);
        __syncthreads();
    }

#pragma unroll
    for (int m = 0; m < 4; ++m)
#pragma unroll
        for (int n = 0; n < N_FR; ++n) {
            int row0o = bm + wr * 64 + m * 16 + kg * 4;
            int col   = bn + wc * (BN / 2) + n * 16 + r;
#pragma unroll
            for (int j = 0; j < 4; ++j) {
                float v = acc[m][n][j];
                if (SILUZ && col >= INNER_) v = siluf(v);
                if (OUTF16) ((f16*)Cout)[(size_t)(row0o + j) * N + col] = (f16)v;
                else        ((float*)Cout)[(size_t)(row0o + j) * N + col] = v;
            }
        }
}

// ---------------- causal conv (K=4) + bias + SiLU + fused dt-projection ----------------
__global__ __launch_bounds__(256) void conv_silu_dt(const f16* __restrict__ xz,
                                                    const float* __restrict__ cw,
                                                    const float* __restrict__ cb,
                                                    const float* __restrict__ Wdt,
                                                    const float* __restrict__ bdt,
                                                    f16* __restrict__ xc,
                                                    float* __restrict__ dtb) {
    __shared__ float sred[4][HEADS_];
    const int m = blockIdx.x;
    const int tid = threadIdx.x;
    const int c8 = tid * 8;
    const int t = m & (L_ - 1);
    float acc[8];
    float4 wv[8];
#pragma unroll
    for (int j = 0; j < 8; ++j) { acc[j] = cb[c8 + j]; wv[j] = *(const float4*)&cw[(c8 + j) * 4]; }
#pragma unroll
    for (int k = 0; k < 4; ++k) {
        int tt = t - 3 + k;
        if (tt >= 0) {
            half8 xv = *(const half8*)&xz[(size_t)(m - 3 + k) * XZS_ + c8];
#pragma unroll
            for (int j = 0; j < 8; ++j) acc[j] += (float)xv[j] * ((const float*)&wv[j])[k];
        }
    }
    float xf[8];
    half8 o;
#pragma unroll
    for (int j = 0; j < 8; ++j) { xf[j] = siluf(acc[j]); o[j] = (f16)xf[j]; }
    *(half8*)&xc[(size_t)m * INNER_ + c8] = o;

    float p[HEADS_];
#pragma unroll
    for (int h = 0; h < HEADS_; ++h) {
        float4 w0 = *(const float4*)&Wdt[h * INNER_ + c8];
        float4 w1 = *(const float4*)&Wdt[h * INNER_ + c8 + 4];
        p[h] = xf[0]*w0.x + xf[1]*w0.y + xf[2]*w0.z + xf[3]*w0.w
             + xf[4]*w1.x + xf[5]*w1.y + xf[6]*w1.z + xf[7]*w1.w;
    }
#pragma unroll
    for (int h = 0; h < HEADS_; ++h)
#pragma unroll
        for (int off = 32; off > 0; off >>= 1)
            p[h] += __shfl_down(p[h], off, 64);
    if ((tid & 63) == 0) {
#pragma unroll
        for (int h = 0; h < HEADS_; ++h) sred[tid >> 6][h] = p[h];
    }
    __syncthreads();
    if (tid < 32) {
        float v = sred[tid >> 3][tid & 7];
        v += __shfl_down(v, 16, 32);
        v += __shfl_down(v, 8, 32);
        if (tid < 8) {
            float s = v + bdt[tid];
            dtb[(size_t)m * HEADS_ + tid] = (s > 20.f) ? s : log1pf(expf(s));
        }
    }
}

// ---------------- per-head transpose + gstat zero ----------------
__global__ __launch_bounds__(256) void xpose_k(const f16* __restrict__ xc,
                                               f16* __restrict__ xT,
                                               float* __restrict__ gstat) {
    __shared__ f16 sT[64][72];
    const int blk = blockIdx.x;
    const int bh = blk >> 7;            // 16
    const int rem = blk & 127;
    const int tt = rem >> 2;            // 32 t-tiles
    const int pt = rem & 3;             // 4 p-tiles
    const int b = bh >> 3, h = bh & 7;
    const int tid = threadIdx.x;
    if (blk == 0 && tid < 2 * B_ * HEADS_) gstat[tid] = 0.f;
#pragma unroll
    for (int it = 0; it < 2; ++it) {
        int q = tid + it * 256;
        int tr = q >> 3;
        int p0 = (q & 7) * 8;
        half8 v = *(const half8*)&xc[(size_t)(b * L_ + tt * 64 + tr) * INNER_ + h * HDIM_ + pt * 64 + p0];
        *(half8*)&sT[tr][p0] = v;
    }
    __syncthreads();
#pragma unroll
    for (int it = 0; it < 2; ++it) {
        int q = tid + it * 256;
        int pr = q >> 3;
        int t0 = (q & 7) * 8;
        half8 v;
#pragma unroll
        for (int j = 0; j < 8; ++j) v[j] = sT[t0 + j][pr];
        *(half8*)&xT[((size_t)bh * HDIM_ + pt * 64 + pr) * L_ + tt * 64 + t0] = v;
    }
}

// ---------------- fused SSD: prefix scan + P=mask(C.B^T) + S^T = X^T.(wB) ----------------
// Replaces ssd_phase1 + bwt_k + ssd_phase2. The w-scaled B^T lives only in LDS
// (XOR-swizzled rows: elem = s*64 + (n ^ ((s&7)<<3)), bijective per 8-row stripe).
__global__ __launch_bounds__(256) void ssd12(const f16* __restrict__ bc,
                                             const float* __restrict__ dtb,
                                             const float* __restrict__ log_a,
                                             const f16* __restrict__ xT,
                                             f16* __restrict__ pbuf,
                                             f16* __restrict__ sloc,
                                             float* __restrict__ eAbuf,
                                             float* __restrict__ cdecay) {
    __shared__ float sA[Q_], sDt[Q_], sw[Q_];
    __shared__ f16 sB[Q_ * Q_];          // 8 KB, w-scaled, swizzled
    const int tid = threadIdx.x;
    const int chunk = blockIdx.x;
    const int bh = chunk / NC_;
    const int ck = chunk - bh * NC_;
    const int b = bh >> 3, h = bh & 7;
    const int m0 = b * L_ + ck * Q_;

    // issue B-tile loads into registers (2 half8 per thread, 512 slots total)
    const int s0 = tid >> 3,        n00 = (tid & 7) * 8;
    const int s1 = (tid + 256) >> 3, n01 = (tid & 7) * 8;   // (tid+256)&7 == tid&7
    half8 bv0 = *(const half8*)&bc[(size_t)(m0 + s0) * BCS_ + h * STATE_ + n00];
    half8 bv1 = *(const half8*)&bc[(size_t)(m0 + s1) * BCS_ + h * STATE_ + n01];

    if (tid < 64) {                // wave 0: inclusive prefix scan of dt*a
        float dt = dtb[(size_t)(m0 + tid) * HEADS_ + h];
        float a = -expf(log_a[h]);
        float x = dt * a;
#pragma unroll
        for (int off = 1; off < 64; off <<= 1) {
            float v = __shfl_up(x, off, 64);
            if (tid >= off) x += v;
        }
        float Alast = __shfl(x, 63, 64);
        sA[tid] = x;
        sDt[tid] = dt;
        sw[tid] = expf(Alast - x) * dt;
        eAbuf[(size_t)(m0 + tid) * HEADS_ + h] = expf(x);
        if (tid == 0) cdecay[chunk] = expf(Alast);
    }
    __syncthreads();

    // w-scaled, swizzled store of B^T source tile
    {
        float w0 = sw[s0], w1 = sw[s1];
        half8 o0, o1;
#pragma unroll
        for (int j = 0; j < 8; ++j) { o0[j] = (f16)((float)bv0[j] * w0); o1[j] = (f16)((float)bv1[j] * w1); }
        *(half8*)&sB[s0 * Q_ + (n00 ^ ((s0 & 7) << 3))] = o0;
        *(half8*)&sB[s1 * Q_ + (n01 ^ ((s1 & 7) << 3))] = o1;
    }

    const int w = tid >> 6, lane = tid & 63;
    const int r = lane & 15, kg = lane >> 4;

    // ---- phase 1: G = C.B^T (operands straight from L2-hot global), masked P ----
    {
        const int ft = w;
        const f16* Crow = bc + (size_t)(m0 + ft * 16 + r) * BCS_ + 512 + h * STATE_;
        half8 a0 = *(const half8*)(Crow + kg * 8);
        half8 a1 = *(const half8*)(Crow + 32 + kg * 8);
#pragma unroll
        for (int fs = 0; fs < 4; ++fs) {
            const f16* Brow = bc + (size_t)(m0 + fs * 16 + r) * BCS_ + h * STATE_;
            half8 b0 = *(const half8*)(Brow + kg * 8);
            half8 b1 = *(const half8*)(Brow + 32 + kg * 8);
            f32x4 g = (f32x4)0.f;
            g = __builtin_amdgcn_mfma_f32_16x16x32_f16(a0, b0, g, 0, 0, 0);
            g = __builtin_amdgcn_mfma_f32_16x16x32_f16(a1, b1, g, 0, 0, 0);
            int s = fs * 16 + r;
            float As = sA[s], dts = sDt[s];
#pragma unroll
            for (int j = 0; j < 4; ++j) {
                int t = ft * 16 + kg * 4 + j;
                float val = (t >= s) ? g[j] * expf(sA[t] - As) * dts : 0.f;
                pbuf[((size_t)chunk * Q_ + t) * Q_ + s] = (f16)val;
            }
        }
    }
    __syncthreads();   // sB ready

    // ---- phase 2: S^T[p][n] = sum_s X^T[p][s] * (w_s B[s][n]) ----
    f32x4 acc[4][4];
#pragma unroll
    for (int i = 0; i < 4; ++i)
#pragma unroll
        for (int j = 0; j < 4; ++j) acc[i][j] = (f32x4)0.f;

#pragma unroll
    for (int kk = 0; kk < 2; ++kk) {
        half8 a[4], bfr[4];
#pragma unroll
        for (int pf = 0; pf < 4; ++pf) {
            int p = w * 64 + pf * 16 + r;
            a[pf] = *(const half8*)&xT[((size_t)bh * HDIM_ + p) * L_ + ck * Q_ + kk * 32 + kg * 8];
        }
#pragma unroll
        for (int nf = 0; nf < 4; ++nf) {
            int n = nf * 16 + r;
            half8 v;
#pragma unroll
            for (int j = 0; j < 8; ++j) {
                int s = kk * 32 + kg * 8 + j;       // (s&7)==j
                v[j] = sB[s * Q_ + (n ^ (j << 3))];
            }
            bfr[nf] = v;
        }
#pragma unroll
        for (int pf = 0; pf < 4; ++pf)
#pragma unroll
            for (int nf = 0; nf < 4; ++nf)
                acc[pf][nf] = __builtin_amdgcn_mfma_f32_16x16x32_f16(a[pf], bfr[nf], acc[pf][nf], 0, 0, 0);
    }
#pragma unroll
    for (int pf = 0; pf < 4; ++pf)
#pragma unroll
        for (int nf = 0; nf < 4; ++nf) {
            int n = nf * 16 + r;
#pragma unroll
            for (int j = 0; j < 4; ++j) {
                int p = w * 64 + pf * 16 + kg * 4 + j;
                sloc[((size_t)chunk * HDIM_ + p) * STATE_ + n] = (f16)acc[pf][nf][j];
            }
        }
}

// ---------------- SSD phase B: sequential inter-chunk state recurrence (half4) ----------------
__global__ __launch_bounds__(256) void chunk_scan_k(f16* __restrict__ sloc,
                                                    const float* __restrict__ cdecay) {
    int bh = blockIdx.x >> 4;                                   // 256 blocks: 16 bh x 16 groups
    int el4 = (((blockIdx.x & 15) * 256 + threadIdx.x) << 2);   // 0..16383 step 4
    float s0 = 0.f, s1 = 0.f, s2 = 0.f, s3 = 0.f;
    for (int c = 0; c < NC_; ++c) {
        size_t chunk = (size_t)bh * NC_ + c;
        f16* ptr = sloc + chunk * (size_t)(STATE_ * HDIM_) + el4;
        half4 v = *(const half4*)ptr;
        half4 o; o[0] = (f16)s0; o[1] = (f16)s1; o[2] = (f16)s2; o[3] = (f16)s3;
        *(half4*)ptr = o;                  // becomes S_in for this chunk
        float d = cdecay[chunk];
        s0 = d * s0 + (float)v[0];
        s1 = d * s1 + (float)v[1];
        s2 = d * s2 + (float)v[2];
        s3 = d * s3 + (float)v[3];
    }
}

// ---------------- SSD phase 3 (MFMA): Y = [P | eA*C].[X^T | S_in^T]^T + d*x ; GN stats ----------------
__global__ __launch_bounds__(256) void ssd_phase3(const f16* __restrict__ bc,
                                                  const f16* __restrict__ pbuf,
                                                  const f16* __restrict__ xT,
                                                  const f16* __restrict__ sloc,
                                                  const f16* __restrict__ xch,
                                                  const float* __restrict__ eAbuf,
                                                  const float* __restrict__ dparam,
                                                  f16* __restrict__ ybuf,
                                                  float* __restrict__ gstats) {
    __shared__ float red[512];
    const int tid = threadIdx.x;
    const int chunk = blockIdx.x;
    const int bh = chunk / NC_;
    const int ck = chunk - bh * NC_;
    const int b = bh >> 3, h = bh & 7;
    const int m0 = b * L_ + ck * Q_;
    const int w = tid >> 6, lane = tid & 63;
    const int r = lane & 15, kg = lane >> 4;

    float eA[4];
#pragma unroll
    for (int ft = 0; ft < 4; ++ft)
        eA[ft] = eAbuf[(size_t)(m0 + ft * 16 + r) * HEADS_ + h];

    f32x4 acc[4][4];
#pragma unroll
    for (int i = 0; i < 4; ++i)
#pragma unroll
        for (int j = 0; j < 4; ++j) acc[i][j] = (f32x4)0.f;

#pragma unroll
    for (int ks = 0; ks < 4; ++ks) {
        half8 a[4], bfr[4];
#pragma unroll
        for (int ft = 0; ft < 4; ++ft) {
            int t = ft * 16 + r;
            if (ks < 2) {
                a[ft] = *(const half8*)&pbuf[((size_t)chunk * Q_ + t) * Q_ + ks * 32 + kg * 8];
            } else {
                half8 c = *(const half8*)&bc[(size_t)(m0 + t) * BCS_ + 512 + h * STATE_ + (ks - 2) * 32 + kg * 8];
                half8 sc;
#pragma unroll
                for (int j = 0; j < 8; ++j) sc[j] = (f16)(eA[ft] * (float)c[j]);
                a[ft] = sc;
            }
        }
#pragma unroll
        for (int pf = 0; pf < 4; ++pf) {
            int p = w * 64 + pf * 16 + r;
            if (ks < 2)
                bfr[pf] = *(const half8*)&xT[((size_t)bh * HDIM_ + p) * L_ + ck * Q_ + ks * 32 + kg * 8];
            else
                bfr[pf] = *(const half8*)&sloc[((size_t)chunk * HDIM_ + p) * STATE_ + (ks - 2) * 32 + kg * 8];
        }
#pragma unroll
        for (int ft = 0; ft < 4; ++ft)
#pragma unroll
            for (int pf = 0; pf < 4; ++pf)
                acc[ft][pf] = __builtin_amdgcn_mfma_f32_16x16x32_f16(a[ft], bfr[pf], acc[ft][pf], 0, 0, 0);
    }

    const float d = dparam[h];
    float lsum = 0.f, lsq = 0.f;
#pragma unroll
    for (int ft = 0; ft < 4; ++ft)
#pragma unroll
        for (int pf = 0; pf < 4; ++pf) {
            int p = w * 64 + pf * 16 + r;
#pragma unroll
            for (int j = 0; j < 4; ++j) {
                int t = ft * 16 + kg * 4 + j;
                size_t off = (size_t)(m0 + t) * INNER_ + h * HDIM_ + p;
                float y = acc[ft][pf][j] + d * (float)xch[off];
                ybuf[off] = (f16)y;
                lsum += y; lsq += y * y;
            }
        }
    __syncthreads();
    red[tid] = lsum; red[256 + tid] = lsq;
    __syncthreads();
    for (int st = 128; st > 0; st >>= 1) {
        if (tid < st) { red[tid] += red[tid + st]; red[256 + tid] += red[256 + tid + st]; }
        __syncthreads();
    }
    if (tid == 0) {
        atomicAdd(&gstats[bh * 2 + 0], red[0]);
        atomicAdd(&gstats[bh * 2 + 1], red[256]);
    }
}

// ---------------- out-GEMM with fused GroupNorm+gate A-staging ----------------
// A-tile computed on the fly: a[m][c] = ((y-mean)*rstd*gnw[c]+gnb[c]) * silu_z[m][c],
// ds_written into the SAME swizzled phys slots the fragment reader expects.
__global__ __launch_bounds__(256) void hgemm_gate(const f16* __restrict__ ybuf,
                                                  const f16* __restrict__ xz,
                                                  const f16* __restrict__ W,
                                                  const float* __restrict__ gstats,
                                                  const f16* __restrict__ gnw,
                                                  const f16* __restrict__ gnb,
                                                  float* __restrict__ Cout) {
    constexpr int BN = 64;
    const int K = INNER_, N = DIM_;
    __shared__ f16 sA[128 * 32];
    __shared__ f16 sW[BN * 32];
    const int tid  = threadIdx.x;
    const int wid  = tid >> 6;
    const int lane = tid & 63;
    const int bm = blockIdx.y * 128;
    const int bn = blockIdx.x * BN;
    const int wr = wid >> 1, wc = wid & 1;
    const int r  = lane & 15, kg = lane >> 4;
    const float INV_CNT = 1.f / ((float)L_ * HDIM_);

    // W staging (gload_lds): slot tid+512
    const int wrow = tid >> 2;
    const int wkgv = (((tid + 512) & 3) ^ ((wrow >> 1) & 3)) * 8;
    const f16* gW = W + (size_t)(bn + wrow >= 0 ? bn + wrow : 0) * K + wkgv;  // wrow in [0,64)? tid>>2 in [0,64)
    f16* lW = &sW[(tid & ~63) * 8];

    int aoff[4], boff[2];
#pragma unroll
    for (int m = 0; m < 4; ++m) {
        int arow = wr * 64 + m * 16 + r;
        aoff[m] = arow * 32 + ((kg ^ ((arow >> 1) & 3)) << 3);
    }
#pragma unroll
    for (int n = 0; n < 2; ++n) {
        int wrw = wc * 32 + n * 16 + r;
        boff[n] = wrw * 32 + ((kg ^ ((wrw >> 1) & 3)) << 3);
    }

    // per-slot constants for the 2 manual A slots
    int srow[2], skgv[2], sm[2];
#pragma unroll
    for (int i = 0; i < 2; ++i) {
        int slot = tid + i * 256;
        srow[i] = slot >> 2;
        skgv[i] = ((slot & 3) ^ ((srow[i] >> 1) & 3)) * 8;
        sm[i] = bm + srow[i];
    }

    half8 pyv[2], psz[2], pgw[2], pgb[2];
    auto loadA = [&](int k0) {
#pragma unroll
        for (int i = 0; i < 2; ++i) {
            int c = k0 + skgv[i];
            pyv[i] = *(const half8*)&ybuf[(size_t)sm[i] * INNER_ + c];
            psz[i] = *(const half8*)&xz[(size_t)sm[i] * XZS_ + INNER_ + c];
            pgw[i] = *(const half8*)&gnw[c];
            pgb[i] = *(const half8*)&gnb[c];
        }
    };
    loadA(0);

    f32x4 acc[4][2];
#pragma unroll
    for (int m = 0; m < 4; ++m)
#pragma unroll
        for (int n = 0; n < 2; ++n) acc[m][n] = (f32x4)0.f;

    for (int k0 = 0; k0 < K; k0 += 32) {
        gload_lds16(gW + k0, lW);
#pragma unroll
        for (int i = 0; i < 2; ++i) {
            int c = k0 + skgv[i];
            int bhid = ((sm[i] >> 11) << 3) + (c >> 8);
            float mean = gstats[bhid * 2] * INV_CNT;
            float var  = gstats[bhid * 2 + 1] * INV_CNT - mean * mean;
            float rstd = rsqrtf(var + EPS_);
            half8 o;
#pragma unroll
            for (int j = 0; j < 8; ++j) {
                float Aj = rstd * (float)pgw[i][j];
                float Cj = (float)pgb[i][j] - mean * Aj;
                float v  = (float)pyv[i][j] * Aj + Cj;
                o[j] = (f16)(v * (float)psz[i][j]);
            }
            *(half8*)&sA[(tid + i * 256) * 8] = o;
        }
        if (k0 + 32 < K) loadA(k0 + 32);   // prefetch next A inputs (hides y/z latency)
        __syncthreads();
        half8 av[4], bv[2];
#pragma unroll
        for (int m = 0; m < 4; ++m) av[m] = *(const half8*)&sA[aoff[m]];
#pragma unroll
        for (int n = 0; n < 2; ++n) bv[n] = *(const half8*)&sW[boff[n]];
#pragma unroll
        for (int m = 0; m < 4; ++m)
#pragma unroll
            for (int n = 0; n < 2; ++n)
                acc[m][n] = __builtin_amdgcn_mfma_f32_16x16x32_f16(av[m], bv[n], acc[m][n], 0, 0, 0);
        __syncthreads();
    }

#pragma unroll
    for (int m = 0; m < 4; ++m)
#pragma unroll
        for (int n = 0; n < 2; ++n) {
            int row0o = bm + wr * 64 + m * 16 + kg * 4;
            int col   = bn + wc * 32 + n * 16 + r;
#pragma unroll
            for (int j = 0; j < 4; ++j)
                Cout[(size_t)(row0o + j) * N + col] = acc[m][n][j];
        }
}

// ---------------- launch ----------------
extern "C" void kernel_launch(void* const* d_in, const int* in_sizes, int n_in,
                              void* d_out, int out_size, void* d_ws, size_t ws_size,
                              hipStream_t stream) {
    const float* input  = (const float*)d_in[0];
    const float* Wx     = (const float*)d_in[1];
    const float* Wz     = (const float*)d_in[2];
    const float* conv_w = (const float*)d_in[3];
    const float* conv_b = (const float*)d_in[4];
    const float* Wb     = (const float*)d_in[5];
    const float* Wc     = (const float*)d_in[6];
    const float* Wdt    = (const float*)d_in[7];
    const float* b_dt   = (const float*)d_in[8];
    const float* log_a  = (const float*)d_in[9];
    const float* d_par  = (const float*)d_in[10];
    const float* gn_w   = (const float*)d_in[11];
    const float* gn_b   = (const float*)d_in[12];
    const float* Wout   = (const float*)d_in[13];
    float* out = (float*)d_out;

    float* ws = (float*)d_ws;
    size_t off = 0;
    auto alloc = [&](size_t nfloats) { float* p = ws + off; off += (nfloats + 63) & ~(size_t)63; return p; };
    f16* input_h = (f16*)alloc((size_t)M_*DIM_/2);
    f16* wxz_h   = (f16*)alloc((size_t)XZS_*DIM_/2);
    f16* wbc_h   = (f16*)alloc((size_t)BCS_*INNER_/2);
    f16* wout_h  = (f16*)alloc((size_t)DIM_*INNER_/2);
    f16* gnw_h   = (f16*)alloc((size_t)INNER_/2);
    f16* gnb_h   = (f16*)alloc((size_t)INNER_/2);
    f16* xz_h    = (f16*)alloc((size_t)M_*XZS_/2);
    f16* xconv_h = (f16*)alloc((size_t)M_*INNER_/2);
    f16* xT_h    = (f16*)alloc((size_t)M_*INNER_/2);
    f16* bcmat_h = (f16*)alloc((size_t)M_*BCS_/2);
    f16* pbuf_h  = (f16*)alloc((size_t)NCHUNK_*Q_*Q_/2);
    f16* sloc_h  = (f16*)alloc((size_t)NCHUNK_*STATE_*HDIM_/2);
    f16* ybuf_h  = (f16*)alloc((size_t)M_*INNER_/2);
    float* dtb   = alloc((size_t)M_*HEADS_);
    float* eAb   = alloc((size_t)M_*HEADS_);
    float* cdec  = alloc((size_t)NCHUNK_);
    float* gstat = alloc((size_t)2*B_*HEADS_);

    dim3 blk(256);

    cast_all<<<12292, blk, 0, stream>>>(input, Wx, Wz, Wb, Wc, Wout, gn_w, gn_b,
                                        input_h, wxz_h, wbc_h, wout_h, gnw_h, gnb_h);
    hgemm<128,true,true><<<dim3(XZS_/128, M_/128), blk, 0, stream>>>(input_h, wxz_h, xz_h, DIM_, XZS_);
    conv_silu_dt<<<M_, blk, 0, stream>>>(xz_h, conv_w, conv_b, Wdt, b_dt, xconv_h, dtb);
    hgemm<64,true,false><<<dim3(BCS_/64, M_/128), blk, 0, stream>>>(xconv_h, wbc_h, bcmat_h, INNER_, BCS_);
    xpose_k<<<2048, blk, 0, stream>>>(xconv_h, xT_h, gstat);
    ssd12<<<NCHUNK_, blk, 0, stream>>>(bcmat_h, dtb, log_a, xT_h, pbuf_h, sloc_h, eAb, cdec);
    chunk_scan_k<<<256, blk, 0, stream>>>(sloc_h, cdec);
    ssd_phase3<<<NCHUNK_, blk, 0, stream>>>(bcmat_h, pbuf_h, xT_h, sloc_h, xconv_h,
                                            eAb, d_par, ybuf_h, gstat);
    hgemm_gate<<<dim3(DIM_/64, M_/128), blk, 0, stream>>>(ybuf_h, xz_h, wout_h, gstat,
                                                          gnw_h, gnb_h, out);
}

// Round 8
// 363.153 us; speedup vs baseline: 1.0568x; 1.0568x over previous
//
#include <hip/hip_runtime.h>
#include <math.h>

// ---------------- problem constants ----------------
#define DIM_   1024
#define STATE_ 64
#define HEADS_ 8
#define INNER_ 2048
#define HDIM_  256          // INNER/HEADS
#define B_     2
#define L_     2048
#define M_     (B_*L_)      // 4096 rows total
#define EPS_   1e-5f
#define Q_     64           // SSD chunk length
#define NC_    (L_/Q_)      // 32 chunks per sequence
#define NCHUNK_ (B_*HEADS_*NC_)  // 512 chunk-blocks
#define BCS_   1024         // combined B|C projection row stride
#define XZS_   4096         // combined x|z row stride

typedef _Float16 f16;
typedef __attribute__((ext_vector_type(8))) _Float16 half8;
typedef __attribute__((ext_vector_type(4))) _Float16 half4;
typedef __attribute__((ext_vector_type(4))) float    f32x4;

__device__ __forceinline__ float siluf(float x) { return x / (1.f + expf(-x)); }

__device__ __forceinline__ void gload_lds16(const void* g, void* l) {
    __builtin_amdgcn_global_load_lds((const __attribute__((address_space(1))) void*)g,
                                     (__attribute__((address_space(3))) void*)l, 16, 0, 0);
}

// ---------------- merged fp32 -> f16 cast of all operands ----------------
__global__ __launch_bounds__(256) void cast_all(const float* __restrict__ in0,
                                                const float* __restrict__ Wx,
                                                const float* __restrict__ Wz,
                                                const float* __restrict__ Wb,
                                                const float* __restrict__ Wc,
                                                const float* __restrict__ Wout,
                                                f16* __restrict__ input_h,
                                                f16* __restrict__ wxz_h,
                                                f16* __restrict__ wbc_h,
                                                f16* __restrict__ wout_h) {
    int i = blockIdx.x * 256 + threadIdx.x;
    const float* src; f16* dst; int off;
    if      (i < 1048576) { src = in0;  dst = input_h;            off = i; }
    else if (i < 1572864) { src = Wx;   dst = wxz_h;              off = i - 1048576; }
    else if (i < 2097152) { src = Wz;   dst = wxz_h + 2097152;    off = i - 1572864; }
    else if (i < 2359296) { src = Wb;   dst = wbc_h;              off = i - 2097152; }
    else if (i < 2621440) { src = Wc;   dst = wbc_h + 1048576;    off = i - 2359296; }
    else                  { src = Wout; dst = wout_h;             off = i - 2621440; }
    float4 v = *(const float4*)&src[(size_t)off * 4];
    half4 o;
    o[0] = (f16)v.x; o[1] = (f16)v.y; o[2] = (f16)v.z; o[3] = (f16)v.w;
    *(half4*)&dst[(size_t)off * 4] = o;
}

// ---------------- f16 MFMA GEMM: C[M x N] = A[M x K] * W[N x K]^T ----------------
// XCD-chunked block swizzle (T1): XCD k processes a contiguous row-major run of
// tiles -> A-slice shared within a bm-row, W panel reused across bm-rows in-chunk.
// SILUZ: apply silu() to output columns >= INNER_ (the z half of xz projection).
template<int BN, bool OUTF16, bool SILUZ>
__global__ __launch_bounds__(256) void hgemm(const f16* __restrict__ A,
                                             const f16* __restrict__ W,
                                             void* __restrict__ Cout,
                                             int K, int N) {
    constexpr int N_FR = BN / 32;            // per-wave n fragments
    constexpr int NITER = (128 + BN) / 64;   // staging issues per thread
    __shared__ f16 sA[128 * 32];
    __shared__ f16 sW[BN * 32];
    const int tid  = threadIdx.x;
    const int wid  = tid >> 6;
    const int lane = tid & 63;

    // bijective XCD swizzle (grids here are multiples of 8)
    const int nwg = gridDim.x * gridDim.y;
    const int id0 = blockIdx.y * gridDim.x + blockIdx.x;
    const int cpx = nwg >> 3;
    const int id  = (id0 & 7) * cpx + (id0 >> 3);
    const int gxsh = __ffs(gridDim.x) - 1;        // gridDim.x is a power of 2
    const int bm = (id >> gxsh) * 128;
    const int bn = (id & (gridDim.x - 1)) * BN;

    const int wr = wid >> 1, wc = wid & 1;
    const int r  = lane & 15, kg = lane >> 4;

    const f16* gsrc[NITER];
    f16* ldst[NITER];
#pragma unroll
    for (int i = 0; i < NITER; ++i) {
        int slot = tid + i * 256;
        if (slot < 512) {
            int row = slot >> 2;
            int kgv = ((slot & 3) ^ ((row >> 1) & 3)) * 8;
            gsrc[i] = A + (size_t)(bm + row) * K + kgv;
        } else {
            int row = (slot - 512) >> 2;
            int kgv = ((slot & 3) ^ ((row >> 1) & 3)) * 8;
            gsrc[i] = W + (size_t)(bn + row) * K + kgv;
        }
        int slot0 = (tid & ~63) + i * 256;   // wave-uniform base slot
        ldst[i] = (slot0 < 512) ? &sA[slot0 * 8] : &sW[(slot0 - 512) * 8];
    }

    int aoff[4], boff[N_FR];
#pragma unroll
    for (int m = 0; m < 4; ++m) {
        int arow = wr * 64 + m * 16 + r;
        aoff[m] = arow * 32 + ((kg ^ ((arow >> 1) & 3)) << 3);
    }
#pragma unroll
    for (int n = 0; n < N_FR; ++n) {
        int wrow = wc * (BN / 2) + n * 16 + r;
        boff[n] = wrow * 32 + ((kg ^ ((wrow >> 1) & 3)) << 3);
    }

    f32x4 acc[4][N_FR];
#pragma unroll
    for (int m = 0; m < 4; ++m)
#pragma unroll
        for (int n = 0; n < N_FR; ++n) acc[m][n] = (f32x4)0.f;

    for (int k0 = 0; k0 < K; k0 += 32) {
#pragma unroll
        for (int i = 0; i < NITER; ++i) gload_lds16(gsrc[i] + k0, ldst[i]);
        __syncthreads();
        half8 av[4], bv[N_FR];
#pragma unroll
        for (int m = 0; m < 4; ++m) av[m] = *(const half8*)&sA[aoff[m]];
#pragma unroll
        for (int n = 0; n < N_FR; ++n) bv[n] = *(const half8*)&sW[boff[n]];
#pragma unroll
        for (int m = 0; m < 4; ++m)
#pragma unroll
            for (int n = 0; n < N_FR; ++n)
                acc[m][n] = __builtin_amdgcn_mfma_f32_16x16x32_f16(av[m], bv[n], acc[m][n], 0, 0, 0);
        __syncthreads();
    }

#pragma unroll
    for (int m = 0; m < 4; ++m)
#pragma unroll
        for (int n = 0; n < N_FR; ++n) {
            int row0o = bm + wr * 64 + m * 16 + kg * 4;
            int col   = bn + wc * (BN / 2) + n * 16 + r;
#pragma unroll
            for (int j = 0; j < 4; ++j) {
                float v = acc[m][n][j];
                if (SILUZ && col >= INNER_) v = siluf(v);
                if (OUTF16) ((f16*)Cout)[(size_t)(row0o + j) * N + col] = (f16)v;
                else        ((float*)Cout)[(size_t)(row0o + j) * N + col] = v;
            }
        }
}

// ---------------- causal conv (K=4) + bias + SiLU + fused dt-projection ----------------
__global__ __launch_bounds__(256) void conv_silu_dt(const f16* __restrict__ xz,
                                                    const float* __restrict__ cw,
                                                    const float* __restrict__ cb,
                                                    const float* __restrict__ Wdt,
                                                    const float* __restrict__ bdt,
                                                    f16* __restrict__ xc,
                                                    float* __restrict__ dtb) {
    __shared__ float sred[4][HEADS_];
    const int m = blockIdx.x;
    const int tid = threadIdx.x;
    const int c8 = tid * 8;
    const int t = m & (L_ - 1);
    float acc[8];
    float4 wv[8];
#pragma unroll
    for (int j = 0; j < 8; ++j) { acc[j] = cb[c8 + j]; wv[j] = *(const float4*)&cw[(c8 + j) * 4]; }
#pragma unroll
    for (int k = 0; k < 4; ++k) {
        int tt = t - 3 + k;
        if (tt >= 0) {
            half8 xv = *(const half8*)&xz[(size_t)(m - 3 + k) * XZS_ + c8];
#pragma unroll
            for (int j = 0; j < 8; ++j) acc[j] += (float)xv[j] * ((const float*)&wv[j])[k];
        }
    }
    float xf[8];
    half8 o;
#pragma unroll
    for (int j = 0; j < 8; ++j) { xf[j] = siluf(acc[j]); o[j] = (f16)xf[j]; }
    *(half8*)&xc[(size_t)m * INNER_ + c8] = o;

    float p[HEADS_];
#pragma unroll
    for (int h = 0; h < HEADS_; ++h) {
        float4 w0 = *(const float4*)&Wdt[h * INNER_ + c8];
        float4 w1 = *(const float4*)&Wdt[h * INNER_ + c8 + 4];
        p[h] = xf[0]*w0.x + xf[1]*w0.y + xf[2]*w0.z + xf[3]*w0.w
             + xf[4]*w1.x + xf[5]*w1.y + xf[6]*w1.z + xf[7]*w1.w;
    }
#pragma unroll
    for (int h = 0; h < HEADS_; ++h)
#pragma unroll
        for (int off = 32; off > 0; off >>= 1)
            p[h] += __shfl_down(p[h], off, 64);
    if ((tid & 63) == 0) {
#pragma unroll
        for (int h = 0; h < HEADS_; ++h) sred[tid >> 6][h] = p[h];
    }
    __syncthreads();
    if (tid < 32) {
        float v = sred[tid >> 3][tid & 7];
        v += __shfl_down(v, 16, 32);
        v += __shfl_down(v, 8, 32);
        if (tid < 8) {
            float s = v + bdt[tid];
            dtb[(size_t)m * HEADS_ + tid] = (s > 20.f) ? s : log1pf(expf(s));
        }
    }
}

// ---------------- per-head transpose + gstat zero ----------------
__global__ __launch_bounds__(256) void xpose_k(const f16* __restrict__ xc,
                                               f16* __restrict__ xT,
                                               float* __restrict__ gstat) {
    __shared__ f16 sT[64][72];
    const int blk = blockIdx.x;
    const int bh = blk >> 7;            // 16
    const int rem = blk & 127;
    const int tt = rem >> 2;            // 32 t-tiles
    const int pt = rem & 3;             // 4 p-tiles
    const int b = bh >> 3, h = bh & 7;
    const int tid = threadIdx.x;
    if (blk == 0 && tid < 2 * B_ * HEADS_) gstat[tid] = 0.f;
#pragma unroll
    for (int it = 0; it < 2; ++it) {
        int q = tid + it * 256;
        int tr = q >> 3;
        int p0 = (q & 7) * 8;
        half8 v = *(const half8*)&xc[(size_t)(b * L_ + tt * 64 + tr) * INNER_ + h * HDIM_ + pt * 64 + p0];
        *(half8*)&sT[tr][p0] = v;
    }
    __syncthreads();
#pragma unroll
    for (int it = 0; it < 2; ++it) {
        int q = tid + it * 256;
        int pr = q >> 3;
        int t0 = (q & 7) * 8;
        half8 v;
#pragma unroll
        for (int j = 0; j < 8; ++j) v[j] = sT[t0 + j][pr];
        *(half8*)&xT[((size_t)bh * HDIM_ + pt * 64 + pr) * L_ + tt * 64 + t0] = v;
    }
}

// ---------------- fused SSD: prefix scan + P=mask(C.B^T) + S^T = X^T.(wB) ----------------
__global__ __launch_bounds__(256) void ssd12(const f16* __restrict__ bc,
                                             const float* __restrict__ dtb,
                                             const float* __restrict__ log_a,
                                             const f16* __restrict__ xT,
                                             f16* __restrict__ pbuf,
                                             f16* __restrict__ sloc,
                                             float* __restrict__ eAbuf,
                                             float* __restrict__ cdecay) {
    __shared__ float sA[Q_], sDt[Q_], sw[Q_];
    __shared__ f16 sB[Q_ * Q_];          // 8 KB, w-scaled, swizzled
    const int tid = threadIdx.x;
    const int chunk = blockIdx.x;
    const int bh = chunk / NC_;
    const int ck = chunk - bh * NC_;
    const int b = bh >> 3, h = bh & 7;
    const int m0 = b * L_ + ck * Q_;

    const int s0 = tid >> 3,        n00 = (tid & 7) * 8;
    const int s1 = (tid + 256) >> 3, n01 = (tid & 7) * 8;
    half8 bv0 = *(const half8*)&bc[(size_t)(m0 + s0) * BCS_ + h * STATE_ + n00];
    half8 bv1 = *(const half8*)&bc[(size_t)(m0 + s1) * BCS_ + h * STATE_ + n01];

    if (tid < 64) {                // wave 0: inclusive prefix scan of dt*a
        float dt = dtb[(size_t)(m0 + tid) * HEADS_ + h];
        float a = -expf(log_a[h]);
        float x = dt * a;
#pragma unroll
        for (int off = 1; off < 64; off <<= 1) {
            float v = __shfl_up(x, off, 64);
            if (tid >= off) x += v;
        }
        float Alast = __shfl(x, 63, 64);
        sA[tid] = x;
        sDt[tid] = dt;
        sw[tid] = expf(Alast - x) * dt;
        eAbuf[(size_t)(m0 + tid) * HEADS_ + h] = expf(x);
        if (tid == 0) cdecay[chunk] = expf(Alast);
    }
    __syncthreads();

    {
        float w0 = sw[s0], w1 = sw[s1];
        half8 o0, o1;
#pragma unroll
        for (int j = 0; j < 8; ++j) { o0[j] = (f16)((float)bv0[j] * w0); o1[j] = (f16)((float)bv1[j] * w1); }
        *(half8*)&sB[s0 * Q_ + (n00 ^ ((s0 & 7) << 3))] = o0;
        *(half8*)&sB[s1 * Q_ + (n01 ^ ((s1 & 7) << 3))] = o1;
    }

    const int w = tid >> 6, lane = tid & 63;
    const int r = lane & 15, kg = lane >> 4;

    // ---- phase 1: G = C.B^T, masked P ----
    {
        const int ft = w;
        const f16* Crow = bc + (size_t)(m0 + ft * 16 + r) * BCS_ + 512 + h * STATE_;
        half8 a0 = *(const half8*)(Crow + kg * 8);
        half8 a1 = *(const half8*)(Crow + 32 + kg * 8);
#pragma unroll
        for (int fs = 0; fs < 4; ++fs) {
            const f16* Brow = bc + (size_t)(m0 + fs * 16 + r) * BCS_ + h * STATE_;
            half8 b0 = *(const half8*)(Brow + kg * 8);
            half8 b1 = *(const half8*)(Brow + 32 + kg * 8);
            f32x4 g = (f32x4)0.f;
            g = __builtin_amdgcn_mfma_f32_16x16x32_f16(a0, b0, g, 0, 0, 0);
            g = __builtin_amdgcn_mfma_f32_16x16x32_f16(a1, b1, g, 0, 0, 0);
            int s = fs * 16 + r;
            float As = sA[s], dts = sDt[s];
#pragma unroll
            for (int j = 0; j < 4; ++j) {
                int t = ft * 16 + kg * 4 + j;
                float val = (t >= s) ? g[j] * expf(sA[t] - As) * dts : 0.f;
                pbuf[((size_t)chunk * Q_ + t) * Q_ + s] = (f16)val;
            }
        }
    }
    __syncthreads();   // sB ready

    // ---- phase 2: S^T[p][n] = sum_s X^T[p][s] * (w_s B[s][n]) ----
    f32x4 acc[4][4];
#pragma unroll
    for (int i = 0; i < 4; ++i)
#pragma unroll
        for (int j = 0; j < 4; ++j) acc[i][j] = (f32x4)0.f;

#pragma unroll
    for (int kk = 0; kk < 2; ++kk) {
        half8 a[4], bfr[4];
#pragma unroll
        for (int pf = 0; pf < 4; ++pf) {
            int p = w * 64 + pf * 16 + r;
            a[pf] = *(const half8*)&xT[((size_t)bh * HDIM_ + p) * L_ + ck * Q_ + kk * 32 + kg * 8];
        }
#pragma unroll
        for (int nf = 0; nf < 4; ++nf) {
            int n = nf * 16 + r;
            half8 v;
#pragma unroll
            for (int j = 0; j < 8; ++j) {
                int s = kk * 32 + kg * 8 + j;       // (s&7)==j
                v[j] = sB[s * Q_ + (n ^ (j << 3))];
            }
            bfr[nf] = v;
        }
#pragma unroll
        for (int pf = 0; pf < 4; ++pf)
#pragma unroll
            for (int nf = 0; nf < 4; ++nf)
                acc[pf][nf] = __builtin_amdgcn_mfma_f32_16x16x32_f16(a[pf], bfr[nf], acc[pf][nf], 0, 0, 0);
    }
#pragma unroll
    for (int pf = 0; pf < 4; ++pf)
#pragma unroll
        for (int nf = 0; nf < 4; ++nf) {
            int n = nf * 16 + r;
#pragma unroll
            for (int j = 0; j < 4; ++j) {
                int p = w * 64 + pf * 16 + kg * 4 + j;
                sloc[((size_t)chunk * HDIM_ + p) * STATE_ + n] = (f16)acc[pf][nf][j];
            }
        }
}

// ---------------- SSD phase B: sequential inter-chunk state recurrence (half4) ----------------
__global__ __launch_bounds__(256) void chunk_scan_k(f16* __restrict__ sloc,
                                                    const float* __restrict__ cdecay) {
    int bh = blockIdx.x >> 4;
    int el4 = (((blockIdx.x & 15) * 256 + threadIdx.x) << 2);
    float s0 = 0.f, s1 = 0.f, s2 = 0.f, s3 = 0.f;
    for (int c = 0; c < NC_; ++c) {
        size_t chunk = (size_t)bh * NC_ + c;
        f16* ptr = sloc + chunk * (size_t)(STATE_ * HDIM_) + el4;
        half4 v = *(const half4*)ptr;
        half4 o; o[0] = (f16)s0; o[1] = (f16)s1; o[2] = (f16)s2; o[3] = (f16)s3;
        *(half4*)ptr = o;
        float d = cdecay[chunk];
        s0 = d * s0 + (float)v[0];
        s1 = d * s1 + (float)v[1];
        s2 = d * s2 + (float)v[2];
        s3 = d * s3 + (float)v[3];
    }
}

// ---------------- SSD phase 3 (MFMA): Y = [P | eA*C].[X^T | S_in^T]^T + d*x ; GN stats ----------------
__global__ __launch_bounds__(256) void ssd_phase3(const f16* __restrict__ bc,
                                                  const f16* __restrict__ pbuf,
                                                  const f16* __restrict__ xT,
                                                  const f16* __restrict__ sloc,
                                                  const f16* __restrict__ xch,
                                                  const float* __restrict__ eAbuf,
                                                  const float* __restrict__ dparam,
                                                  f16* __restrict__ ybuf,
                                                  float* __restrict__ gstats) {
    __shared__ float red[512];
    const int tid = threadIdx.x;
    const int chunk = blockIdx.x;
    const int bh = chunk / NC_;
    const int ck = chunk - bh * NC_;
    const int b = bh >> 3, h = bh & 7;
    const int m0 = b * L_ + ck * Q_;
    const int w = tid >> 6, lane = tid & 63;
    const int r = lane & 15, kg = lane >> 4;

    float eA[4];
#pragma unroll
    for (int ft = 0; ft < 4; ++ft)
        eA[ft] = eAbuf[(size_t)(m0 + ft * 16 + r) * HEADS_ + h];

    f32x4 acc[4][4];
#pragma unroll
    for (int i = 0; i < 4; ++i)
#pragma unroll
        for (int j = 0; j < 4; ++j) acc[i][j] = (f32x4)0.f;

#pragma unroll
    for (int ks = 0; ks < 4; ++ks) {
        half8 a[4], bfr[4];
#pragma unroll
        for (int ft = 0; ft < 4; ++ft) {
            int t = ft * 16 + r;
            if (ks < 2) {
                a[ft] = *(const half8*)&pbuf[((size_t)chunk * Q_ + t) * Q_ + ks * 32 + kg * 8];
            } else {
                half8 c = *(const half8*)&bc[(size_t)(m0 + t) * BCS_ + 512 + h * STATE_ + (ks - 2) * 32 + kg * 8];
                half8 sc;
#pragma unroll
                for (int j = 0; j < 8; ++j) sc[j] = (f16)(eA[ft] * (float)c[j]);
                a[ft] = sc;
            }
        }
#pragma unroll
        for (int pf = 0; pf < 4; ++pf) {
            int p = w * 64 + pf * 16 + r;
            if (ks < 2)
                bfr[pf] = *(const half8*)&xT[((size_t)bh * HDIM_ + p) * L_ + ck * Q_ + ks * 32 + kg * 8];
            else
                bfr[pf] = *(const half8*)&sloc[((size_t)chunk * HDIM_ + p) * STATE_ + (ks - 2) * 32 + kg * 8];
        }
#pragma unroll
        for (int ft = 0; ft < 4; ++ft)
#pragma unroll
            for (int pf = 0; pf < 4; ++pf)
                acc[ft][pf] = __builtin_amdgcn_mfma_f32_16x16x32_f16(a[ft], bfr[pf], acc[ft][pf], 0, 0, 0);
    }

    const float d = dparam[h];
    float lsum = 0.f, lsq = 0.f;
#pragma unroll
    for (int ft = 0; ft < 4; ++ft)
#pragma unroll
        for (int pf = 0; pf < 4; ++pf) {
            int p = w * 64 + pf * 16 + r;
#pragma unroll
            for (int j = 0; j < 4; ++j) {
                int t = ft * 16 + kg * 4 + j;
                size_t off = (size_t)(m0 + t) * INNER_ + h * HDIM_ + p;
                float y = acc[ft][pf][j] + d * (float)xch[off];
                ybuf[off] = (f16)y;
                lsum += y; lsq += y * y;
            }
        }
    __syncthreads();
    red[tid] = lsum; red[256 + tid] = lsq;
    __syncthreads();
    for (int st = 128; st > 0; st >>= 1) {
        if (tid < st) { red[tid] += red[tid + st]; red[256 + tid] += red[256 + tid + st]; }
        __syncthreads();
    }
    if (tid == 0) {
        atomicAdd(&gstats[bh * 2 + 0], red[0]);
        atomicAdd(&gstats[bh * 2 + 1], red[256]);
    }
}

// ---------------- GroupNorm finalize + gate (z already silu'd) ----------------
__global__ __launch_bounds__(256) void gn_gate_h(const f16* __restrict__ ybuf,
                                                 const f16* __restrict__ xz,
                                                 const float* __restrict__ gstats,
                                                 const float* __restrict__ gnw,
                                                 const float* __restrict__ gnb,
                                                 f16* __restrict__ g) {
    int idx = blockIdx.x * 256 + threadIdx.x;    // over M_*INNER_/8
    int c8 = (idx & (INNER_/8 - 1)) * 8;
    int m = idx >> 8;
    int bh = (m >> 11) * HEADS_ + (c8 >> 8);
    const float cnt = (float)(L_ * HDIM_);
    float mean = gstats[bh*2] / cnt;
    float var  = gstats[bh*2+1] / cnt - mean*mean;
    float rstd = rsqrtf(var + EPS_);
    size_t off = (size_t)m * INNER_ + c8;
    half8 yv = *(const half8*)&ybuf[off];
    half8 zv = *(const half8*)&xz[(size_t)m * XZS_ + INNER_ + c8];   // pre-silu'd
    float4 w0 = *(const float4*)&gnw[c8], w1 = *(const float4*)&gnw[c8+4];
    float4 b0 = *(const float4*)&gnb[c8], b1 = *(const float4*)&gnb[c8+4];
    float wv[8] = {w0.x, w0.y, w0.z, w0.w, w1.x, w1.y, w1.z, w1.w};
    float bv[8] = {b0.x, b0.y, b0.z, b0.w, b1.x, b1.y, b1.z, b1.w};
    half8 o;
#pragma unroll
    for (int j = 0; j < 8; ++j) {
        float v = ((float)yv[j] - mean) * rstd * wv[j] + bv[j];
        o[j] = (f16)(v * (float)zv[j]);
    }
    *(half8*)&g[off] = o;
}

// ---------------- launch ----------------
extern "C" void kernel_launch(void* const* d_in, const int* in_sizes, int n_in,
                              void* d_out, int out_size, void* d_ws, size_t ws_size,
                              hipStream_t stream) {
    const float* input  = (const float*)d_in[0];
    const float* Wx     = (const float*)d_in[1];
    const float* Wz     = (const float*)d_in[2];
    const float* conv_w = (const float*)d_in[3];
    const float* conv_b = (const float*)d_in[4];
    const float* Wb     = (const float*)d_in[5];
    const float* Wc     = (const float*)d_in[6];
    const float* Wdt    = (const float*)d_in[7];
    const float* b_dt   = (const float*)d_in[8];
    const float* log_a  = (const float*)d_in[9];
    const float* d_par  = (const float*)d_in[10];
    const float* gn_w   = (const float*)d_in[11];
    const float* gn_b   = (const float*)d_in[12];
    const float* Wout   = (const float*)d_in[13];
    float* out = (float*)d_out;

    float* ws = (float*)d_ws;
    size_t off = 0;
    auto alloc = [&](size_t nfloats) { float* p = ws + off; off += (nfloats + 63) & ~(size_t)63; return p; };
    f16* input_h = (f16*)alloc((size_t)M_*DIM_/2);
    f16* wxz_h   = (f16*)alloc((size_t)XZS_*DIM_/2);
    f16* wbc_h   = (f16*)alloc((size_t)BCS_*INNER_/2);
    f16* wout_h  = (f16*)alloc((size_t)DIM_*INNER_/2);
    f16* xz_h    = (f16*)alloc((size_t)M_*XZS_/2);
    f16* xconv_h = (f16*)alloc((size_t)M_*INNER_/2);
    f16* xT_h    = (f16*)alloc((size_t)M_*INNER_/2);
    f16* gbuf_h  = (f16*)alloc((size_t)M_*INNER_/2);
    f16* bcmat_h = (f16*)alloc((size_t)M_*BCS_/2);
    f16* pbuf_h  = (f16*)alloc((size_t)NCHUNK_*Q_*Q_/2);
    f16* sloc_h  = (f16*)alloc((size_t)NCHUNK_*STATE_*HDIM_/2);
    f16* ybuf_h  = (f16*)alloc((size_t)M_*INNER_/2);
    float* dtb   = alloc((size_t)M_*HEADS_);
    float* eAb   = alloc((size_t)M_*HEADS_);
    float* cdec  = alloc((size_t)NCHUNK_);
    float* gstat = alloc((size_t)2*B_*HEADS_);

    dim3 blk(256);

    cast_all<<<12288, blk, 0, stream>>>(input, Wx, Wz, Wb, Wc, Wout,
                                        input_h, wxz_h, wbc_h, wout_h);
    hgemm<128,true,true><<<dim3(XZS_/128, M_/128), blk, 0, stream>>>(input_h, wxz_h, xz_h, DIM_, XZS_);
    conv_silu_dt<<<M_, blk, 0, stream>>>(xz_h, conv_w, conv_b, Wdt, b_dt, xconv_h, dtb);
    hgemm<64,true,false><<<dim3(BCS_/64, M_/128), blk, 0, stream>>>(xconv_h, wbc_h, bcmat_h, INNER_, BCS_);
    xpose_k<<<2048, blk, 0, stream>>>(xconv_h, xT_h, gstat);
    ssd12<<<NCHUNK_, blk, 0, stream>>>(bcmat_h, dtb, log_a, xT_h, pbuf_h, sloc_h, eAb, cdec);
    chunk_scan_k<<<256, blk, 0, stream>>>(sloc_h, cdec);
    ssd_phase3<<<NCHUNK_, blk, 0, stream>>>(bcmat_h, pbuf_h, xT_h, sloc_h, xconv_h,
                                            eAb, d_par, ybuf_h, gstat);
    gn_gate_h<<<(M_*(INNER_/8))/256, blk, 0, stream>>>(ybuf_h, xz_h, gstat, gn_w, gn_b, gbuf_h);
    hgemm<64,false,false><<<dim3(DIM_/64, M_/128), blk, 0, stream>>>(gbuf_h, wout_h, out, INNER_, DIM_);
}

// Round 9
// 349.002 us; speedup vs baseline: 1.0997x; 1.0405x over previous
//
#include <hip/hip_runtime.h>
#include <math.h>

// ---------------- problem constants ----------------
#define DIM_   1024
#define STATE_ 64
#define HEADS_ 8
#define INNER_ 2048
#define HDIM_  256          // INNER/HEADS
#define B_     2
#define L_     2048
#define M_     (B_*L_)      // 4096 rows total
#define EPS_   1e-5f
#define Q_     64           // SSD chunk length
#define NC_    (L_/Q_)      // 32 chunks per sequence
#define NCHUNK_ (B_*HEADS_*NC_)  // 512 chunk-blocks
#define BCS_   1024         // combined B|C projection row stride
#define XZS_   4096         // combined x|z row stride

typedef _Float16 f16;
typedef __attribute__((ext_vector_type(8))) _Float16 half8;
typedef __attribute__((ext_vector_type(4))) _Float16 half4;
typedef __attribute__((ext_vector_type(4))) float    f32x4;

__device__ __forceinline__ float siluf(float x) { return x / (1.f + expf(-x)); }

__device__ __forceinline__ void gload_lds16(const void* g, void* l) {
    __builtin_amdgcn_global_load_lds((const __attribute__((address_space(1))) void*)g,
                                     (__attribute__((address_space(3))) void*)l, 16, 0, 0);
}

// ---------------- merged fp32 -> f16 cast of all operands ----------------
__global__ __launch_bounds__(256) void cast_all(const float* __restrict__ in0,
                                                const float* __restrict__ Wx,
                                                const float* __restrict__ Wz,
                                                const float* __restrict__ Wb,
                                                const float* __restrict__ Wc,
                                                const float* __restrict__ Wout,
                                                f16* __restrict__ input_h,
                                                f16* __restrict__ wxz_h,
                                                f16* __restrict__ wbc_h,
                                                f16* __restrict__ wout_h) {
    int i = blockIdx.x * 256 + threadIdx.x;
    const float* src; f16* dst; int off;
    if      (i < 1048576) { src = in0;  dst = input_h;            off = i; }
    else if (i < 1572864) { src = Wx;   dst = wxz_h;              off = i - 1048576; }
    else if (i < 2097152) { src = Wz;   dst = wxz_h + 2097152;    off = i - 1572864; }
    else if (i < 2359296) { src = Wb;   dst = wbc_h;              off = i - 2097152; }
    else if (i < 2621440) { src = Wc;   dst = wbc_h + 1048576;    off = i - 2359296; }
    else                  { src = Wout; dst = wout_h;             off = i - 2621440; }
    float4 v = *(const float4*)&src[(size_t)off * 4];
    half4 o;
    o[0] = (f16)v.x; o[1] = (f16)v.y; o[2] = (f16)v.z; o[3] = (f16)v.w;
    *(half4*)&dst[(size_t)off * 4] = o;
}

// ---------------- f16 MFMA GEMM: C[M x N] = A[M x K] * W[N x K]^T ----------------
// BM=128, BK=64, natural block mapping. Rows are 128 B (8 x 16B chunks);
// swizzle: phys chunk = logical chunk ^ (row & 7) (involution, 2-way banks = free).
// SILUZ: apply silu() to output columns >= INNER_ (the z half of xz projection).
template<int BN, bool OUTF16, bool SILUZ>
__global__ __launch_bounds__(256) void hgemm(const f16* __restrict__ A,
                                             const f16* __restrict__ W,
                                             void* __restrict__ Cout,
                                             int K, int N) {
    constexpr int N_FR = BN / 32;            // per-wave n fragments
    constexpr int NITER = (128 + BN) / 32;   // staging issues per thread (8 slots/row)
    __shared__ f16 sA[128 * 64];
    __shared__ f16 sW[BN * 64];
    const int tid  = threadIdx.x;
    const int wid  = tid >> 6;
    const int lane = tid & 63;
    const int bm = blockIdx.y * 128;
    const int bn = blockIdx.x * BN;
    const int wr = wid >> 1, wc = wid & 1;
    const int r  = lane & 15, kg = lane >> 4;

    const f16* gsrc[NITER];
    f16* ldst[NITER];
#pragma unroll
    for (int i = 0; i < NITER; ++i) {
        int slot = tid + i * 256;            // 8 slots per 64-f16 row
        if (slot < 1024) {
            int row = slot >> 3;
            int col = ((slot & 7) ^ (row & 7)) * 8;
            gsrc[i] = A + (size_t)(bm + row) * K + col;
        } else {
            int row = (slot - 1024) >> 3;
            int col = ((slot & 7) ^ (row & 7)) * 8;
            gsrc[i] = W + (size_t)(bn + row) * K + col;
        }
        int slot0 = (tid & ~63) + i * 256;   // wave-uniform base slot
        ldst[i] = (slot0 < 1024) ? &sA[slot0 * 8] : &sW[(slot0 - 1024) * 8];
    }

    int abase[4], axor[4], bbase[N_FR], bxor[N_FR];
#pragma unroll
    for (int m = 0; m < 4; ++m) {
        int arow = wr * 64 + m * 16 + r;
        abase[m] = arow * 64; axor[m] = arow & 7;
    }
#pragma unroll
    for (int n = 0; n < N_FR; ++n) {
        int wrow = wc * (BN / 2) + n * 16 + r;
        bbase[n] = wrow * 64; bxor[n] = wrow & 7;
    }

    f32x4 acc[4][N_FR];
#pragma unroll
    for (int m = 0; m < 4; ++m)
#pragma unroll
        for (int n = 0; n < N_FR; ++n) acc[m][n] = (f32x4)0.f;

    for (int k0 = 0; k0 < K; k0 += 64) {
#pragma unroll
        for (int i = 0; i < NITER; ++i) gload_lds16(gsrc[i] + k0, ldst[i]);
        __syncthreads();                     // tiles ready
#pragma unroll
        for (int kk = 0; kk < 2; ++kk) {
            half8 av[4], bv[N_FR];
#pragma unroll
            for (int m = 0; m < 4; ++m)
                av[m] = *(const half8*)&sA[abase[m] + ((((kk << 2) | kg)) ^ axor[m]) * 8];
#pragma unroll
            for (int n = 0; n < N_FR; ++n)
                bv[n] = *(const half8*)&sW[bbase[n] + ((((kk << 2) | kg)) ^ bxor[n]) * 8];
#pragma unroll
            for (int m = 0; m < 4; ++m)
#pragma unroll
                for (int n = 0; n < N_FR; ++n)
                    acc[m][n] = __builtin_amdgcn_mfma_f32_16x16x32_f16(av[m], bv[n], acc[m][n], 0, 0, 0);
        }
        __syncthreads();                     // reads done before next overwrite
    }

#pragma unroll
    for (int m = 0; m < 4; ++m)
#pragma unroll
        for (int n = 0; n < N_FR; ++n) {
            int row0o = bm + wr * 64 + m * 16 + kg * 4;
            int col   = bn + wc * (BN / 2) + n * 16 + r;
#pragma unroll
            for (int j = 0; j < 4; ++j) {
                float v = acc[m][n][j];
                if (SILUZ && col >= INNER_) v = siluf(v);
                if (OUTF16) ((f16*)Cout)[(size_t)(row0o + j) * N + col] = (f16)v;
                else        ((float*)Cout)[(size_t)(row0o + j) * N + col] = v;
            }
        }
}

// ---------------- causal conv (K=4) + bias + SiLU + fused dt-projection ----------------
__global__ __launch_bounds__(256) void conv_silu_dt(const f16* __restrict__ xz,
                                                    const float* __restrict__ cw,
                                                    const float* __restrict__ cb,
                                                    const float* __restrict__ Wdt,
                                                    const float* __restrict__ bdt,
                                                    f16* __restrict__ xc,
                                                    float* __restrict__ dtb) {
    __shared__ float sred[4][HEADS_];
    const int m = blockIdx.x;
    const int tid = threadIdx.x;
    const int c8 = tid * 8;
    const int t = m & (L_ - 1);
    float acc[8];
    float4 wv[8];
#pragma unroll
    for (int j = 0; j < 8; ++j) { acc[j] = cb[c8 + j]; wv[j] = *(const float4*)&cw[(c8 + j) * 4]; }
#pragma unroll
    for (int k = 0; k < 4; ++k) {
        int tt = t - 3 + k;
        if (tt >= 0) {
            half8 xv = *(const half8*)&xz[(size_t)(m - 3 + k) * XZS_ + c8];
#pragma unroll
            for (int j = 0; j < 8; ++j) acc[j] += (float)xv[j] * ((const float*)&wv[j])[k];
        }
    }
    float xf[8];
    half8 o;
#pragma unroll
    for (int j = 0; j < 8; ++j) { xf[j] = siluf(acc[j]); o[j] = (f16)xf[j]; }
    *(half8*)&xc[(size_t)m * INNER_ + c8] = o;

    float p[HEADS_];
#pragma unroll
    for (int h = 0; h < HEADS_; ++h) {
        float4 w0 = *(const float4*)&Wdt[h * INNER_ + c8];
        float4 w1 = *(const float4*)&Wdt[h * INNER_ + c8 + 4];
        p[h] = xf[0]*w0.x + xf[1]*w0.y + xf[2]*w0.z + xf[3]*w0.w
             + xf[4]*w1.x + xf[5]*w1.y + xf[6]*w1.z + xf[7]*w1.w;
    }
#pragma unroll
    for (int h = 0; h < HEADS_; ++h)
#pragma unroll
        for (int off = 32; off > 0; off >>= 1)
            p[h] += __shfl_down(p[h], off, 64);
    if ((tid & 63) == 0) {
#pragma unroll
        for (int h = 0; h < HEADS_; ++h) sred[tid >> 6][h] = p[h];
    }
    __syncthreads();
    if (tid < 32) {
        float v = sred[tid >> 3][tid & 7];
        v += __shfl_down(v, 16, 32);
        v += __shfl_down(v, 8, 32);
        if (tid < 8) {
            float s = v + bdt[tid];
            dtb[(size_t)m * HEADS_ + tid] = (s > 20.f) ? s : log1pf(expf(s));
        }
    }
}

// ---------------- per-head transpose + gstat zero ----------------
__global__ __launch_bounds__(256) void xpose_k(const f16* __restrict__ xc,
                                               f16* __restrict__ xT,
                                               float* __restrict__ gstat) {
    __shared__ f16 sT[64][72];
    const int blk = blockIdx.x;
    const int bh = blk >> 7;            // 16
    const int rem = blk & 127;
    const int tt = rem >> 2;            // 32 t-tiles
    const int pt = rem & 3;             // 4 p-tiles
    const int b = bh >> 3, h = bh & 7;
    const int tid = threadIdx.x;
    if (blk == 0 && tid < 2 * B_ * HEADS_) gstat[tid] = 0.f;
#pragma unroll
    for (int it = 0; it < 2; ++it) {
        int q = tid + it * 256;
        int tr = q >> 3;
        int p0 = (q & 7) * 8;
        half8 v = *(const half8*)&xc[(size_t)(b * L_ + tt * 64 + tr) * INNER_ + h * HDIM_ + pt * 64 + p0];
        *(half8*)&sT[tr][p0] = v;
    }
    __syncthreads();
#pragma unroll
    for (int it = 0; it < 2; ++it) {
        int q = tid + it * 256;
        int pr = q >> 3;
        int t0 = (q & 7) * 8;
        half8 v;
#pragma unroll
        for (int j = 0; j < 8; ++j) v[j] = sT[t0 + j][pr];
        *(half8*)&xT[((size_t)bh * HDIM_ + pt * 64 + pr) * L_ + tt * 64 + t0] = v;
    }
}

// ---------------- fused SSD: prefix scan + P=mask(C.B^T)+d*I + S^T = X^T.(wB) ----------------
__global__ __launch_bounds__(256) void ssd12(const f16* __restrict__ bc,
                                             const float* __restrict__ dtb,
                                             const float* __restrict__ log_a,
                                             const float* __restrict__ dparam,
                                             const f16* __restrict__ xT,
                                             f16* __restrict__ pbuf,
                                             f16* __restrict__ sloc,
                                             float* __restrict__ eAbuf,
                                             float* __restrict__ cdecay) {
    __shared__ float sA[Q_], sDt[Q_], sw[Q_];
    __shared__ f16 sB[Q_ * Q_];          // 8 KB, w-scaled, swizzled
    const int tid = threadIdx.x;
    const int chunk = blockIdx.x;
    const int bh = chunk / NC_;
    const int ck = chunk - bh * NC_;
    const int b = bh >> 3, h = bh & 7;
    const int m0 = b * L_ + ck * Q_;

    const int s0 = tid >> 3,        n00 = (tid & 7) * 8;
    const int s1 = (tid + 256) >> 3, n01 = (tid & 7) * 8;
    half8 bv0 = *(const half8*)&bc[(size_t)(m0 + s0) * BCS_ + h * STATE_ + n00];
    half8 bv1 = *(const half8*)&bc[(size_t)(m0 + s1) * BCS_ + h * STATE_ + n01];

    if (tid < 64) {                // wave 0: inclusive prefix scan of dt*a
        float dt = dtb[(size_t)(m0 + tid) * HEADS_ + h];
        float a = -expf(log_a[h]);
        float x = dt * a;
#pragma unroll
        for (int off = 1; off < 64; off <<= 1) {
            float v = __shfl_up(x, off, 64);
            if (tid >= off) x += v;
        }
        float Alast = __shfl(x, 63, 64);
        sA[tid] = x;
        sDt[tid] = dt;
        sw[tid] = expf(Alast - x) * dt;
        eAbuf[(size_t)(m0 + tid) * HEADS_ + h] = expf(x);
        if (tid == 0) cdecay[chunk] = expf(Alast);
    }
    __syncthreads();

    {
        float w0 = sw[s0], w1 = sw[s1];
        half8 o0, o1;
#pragma unroll
        for (int j = 0; j < 8; ++j) { o0[j] = (f16)((float)bv0[j] * w0); o1[j] = (f16)((float)bv1[j] * w1); }
        *(half8*)&sB[s0 * Q_ + (n00 ^ ((s0 & 7) << 3))] = o0;
        *(half8*)&sB[s1 * Q_ + (n01 ^ ((s1 & 7) << 3))] = o1;
    }

    const int w = tid >> 6, lane = tid & 63;
    const int r = lane & 15, kg = lane >> 4;

    // ---- phase 1: G = C.B^T, masked P, + d on the diagonal (folds d*x into P.X^T) ----
    {
        const float dpar = dparam[h];
        const int ft = w;
        const f16* Crow = bc + (size_t)(m0 + ft * 16 + r) * BCS_ + 512 + h * STATE_;
        half8 a0 = *(const half8*)(Crow + kg * 8);
        half8 a1 = *(const half8*)(Crow + 32 + kg * 8);
#pragma unroll
        for (int fs = 0; fs < 4; ++fs) {
            const f16* Brow = bc + (size_t)(m0 + fs * 16 + r) * BCS_ + h * STATE_;
            half8 b0 = *(const half8*)(Brow + kg * 8);
            half8 b1 = *(const half8*)(Brow + 32 + kg * 8);
            f32x4 g = (f32x4)0.f;
            g = __builtin_amdgcn_mfma_f32_16x16x32_f16(a0, b0, g, 0, 0, 0);
            g = __builtin_amdgcn_mfma_f32_16x16x32_f16(a1, b1, g, 0, 0, 0);
            int s = fs * 16 + r;
            float As = sA[s], dts = sDt[s];
#pragma unroll
            for (int j = 0; j < 4; ++j) {
                int t = ft * 16 + kg * 4 + j;
                float val = (t >= s) ? g[j] * expf(sA[t] - As) * dts : 0.f;
                if (t == s) val += dpar;
                pbuf[((size_t)chunk * Q_ + t) * Q_ + s] = (f16)val;
            }
        }
    }
    __syncthreads();   // sB ready

    // ---- phase 2: S^T[p][n] = sum_s X^T[p][s] * (w_s B[s][n]) ----
    f32x4 acc[4][4];
#pragma unroll
    for (int i = 0; i < 4; ++i)
#pragma unroll
        for (int j = 0; j < 4; ++j) acc[i][j] = (f32x4)0.f;

#pragma unroll
    for (int kk = 0; kk < 2; ++kk) {
        half8 a[4], bfr[4];
#pragma unroll
        for (int pf = 0; pf < 4; ++pf) {
            int p = w * 64 + pf * 16 + r;
            a[pf] = *(const half8*)&xT[((size_t)bh * HDIM_ + p) * L_ + ck * Q_ + kk * 32 + kg * 8];
        }
#pragma unroll
        for (int nf = 0; nf < 4; ++nf) {
            int n = nf * 16 + r;
            half8 v;
#pragma unroll
            for (int j = 0; j < 8; ++j) {
                int s = kk * 32 + kg * 8 + j;       // (s&7)==j
                v[j] = sB[s * Q_ + (n ^ (j << 3))];
            }
            bfr[nf] = v;
        }
#pragma unroll
        for (int pf = 0; pf < 4; ++pf)
#pragma unroll
            for (int nf = 0; nf < 4; ++nf)
                acc[pf][nf] = __builtin_amdgcn_mfma_f32_16x16x32_f16(a[pf], bfr[nf], acc[pf][nf], 0, 0, 0);
    }
#pragma unroll
    for (int pf = 0; pf < 4; ++pf)
#pragma unroll
        for (int nf = 0; nf < 4; ++nf) {
            int n = nf * 16 + r;
#pragma unroll
            for (int j = 0; j < 4; ++j) {
                int p = w * 64 + pf * 16 + kg * 4 + j;
                sloc[((size_t)chunk * HDIM_ + p) * STATE_ + n] = (f16)acc[pf][nf][j];
            }
        }
}

// ---------------- SSD phase B: sequential inter-chunk state recurrence (half4) ----------------
__global__ __launch_bounds__(256) void chunk_scan_k(f16* __restrict__ sloc,
                                                    const float* __restrict__ cdecay) {
    int bh = blockIdx.x >> 4;
    int el4 = (((blockIdx.x & 15) * 256 + threadIdx.x) << 2);
    float s0 = 0.f, s1 = 0.f, s2 = 0.f, s3 = 0.f;
    for (int c = 0; c < NC_; ++c) {
        size_t chunk = (size_t)bh * NC_ + c;
        f16* ptr = sloc + chunk * (size_t)(STATE_ * HDIM_) + el4;
        half4 v = *(const half4*)ptr;
        half4 o; o[0] = (f16)s0; o[1] = (f16)s1; o[2] = (f16)s2; o[3] = (f16)s3;
        *(half4*)ptr = o;
        float d = cdecay[chunk];
        s0 = d * s0 + (float)v[0];
        s1 = d * s1 + (float)v[1];
        s2 = d * s2 + (float)v[2];
        s3 = d * s3 + (float)v[3];
    }
}

// ---------------- SSD phase 3 (MFMA): Y = [P | eA*C].[X^T | S_in^T]^T ; GN stats ----------------
__global__ __launch_bounds__(256) void ssd_phase3(const f16* __restrict__ bc,
                                                  const f16* __restrict__ pbuf,
                                                  const f16* __restrict__ xT,
                                                  const f16* __restrict__ sloc,
                                                  const float* __restrict__ eAbuf,
                                                  float* __restrict__ ybuf16_,  // f16 out
                                                  float* __restrict__ gstats) {
    f16* ybuf = (f16*)ybuf16_;
    __shared__ float red[512];
    const int tid = threadIdx.x;
    const int chunk = blockIdx.x;
    const int bh = chunk / NC_;
    const int ck = chunk - bh * NC_;
    const int b = bh >> 3, h = bh & 7;
    const int m0 = b * L_ + ck * Q_;
    const int w = tid >> 6, lane = tid & 63;
    const int r = lane & 15, kg = lane >> 4;

    float eA[4];
#pragma unroll
    for (int ft = 0; ft < 4; ++ft)
        eA[ft] = eAbuf[(size_t)(m0 + ft * 16 + r) * HEADS_ + h];

    f32x4 acc[4][4];
#pragma unroll
    for (int i = 0; i < 4; ++i)
#pragma unroll
        for (int j = 0; j < 4; ++j) acc[i][j] = (f32x4)0.f;

#pragma unroll
    for (int ks = 0; ks < 4; ++ks) {
        half8 a[4], bfr[4];
#pragma unroll
        for (int ft = 0; ft < 4; ++ft) {
            int t = ft * 16 + r;
            if (ks < 2) {
                a[ft] = *(const half8*)&pbuf[((size_t)chunk * Q_ + t) * Q_ + ks * 32 + kg * 8];
            } else {
                half8 c = *(const half8*)&bc[(size_t)(m0 + t) * BCS_ + 512 + h * STATE_ + (ks - 2) * 32 + kg * 8];
                half8 sc;
#pragma unroll
                for (int j = 0; j < 8; ++j) sc[j] = (f16)(eA[ft] * (float)c[j]);
                a[ft] = sc;
            }
        }
#pragma unroll
        for (int pf = 0; pf < 4; ++pf) {
            int p = w * 64 + pf * 16 + r;
            if (ks < 2)
                bfr[pf] = *(const half8*)&xT[((size_t)bh * HDIM_ + p) * L_ + ck * Q_ + ks * 32 + kg * 8];
            else
                bfr[pf] = *(const half8*)&sloc[((size_t)chunk * HDIM_ + p) * STATE_ + (ks - 2) * 32 + kg * 8];
        }
#pragma unroll
        for (int ft = 0; ft < 4; ++ft)
#pragma unroll
            for (int pf = 0; pf < 4; ++pf)
                acc[ft][pf] = __builtin_amdgcn_mfma_f32_16x16x32_f16(a[ft], bfr[pf], acc[ft][pf], 0, 0, 0);
    }

    float lsum = 0.f, lsq = 0.f;
#pragma unroll
    for (int ft = 0; ft < 4; ++ft)
#pragma unroll
        for (int pf = 0; pf < 4; ++pf) {
            int p = w * 64 + pf * 16 + r;
#pragma unroll
            for (int j = 0; j < 4; ++j) {
                int t = ft * 16 + kg * 4 + j;
                size_t off = (size_t)(m0 + t) * INNER_ + h * HDIM_ + p;
                float y = acc[ft][pf][j];
                ybuf[off] = (f16)y;
                lsum += y; lsq += y * y;
            }
        }
    __syncthreads();
    red[tid] = lsum; red[256 + tid] = lsq;
    __syncthreads();
    for (int st = 128; st > 0; st >>= 1) {
        if (tid < st) { red[tid] += red[tid + st]; red[256 + tid] += red[256 + tid + st]; }
        __syncthreads();
    }
    if (tid == 0) {
        atomicAdd(&gstats[bh * 2 + 0], red[0]);
        atomicAdd(&gstats[bh * 2 + 1], red[256]);
    }
}

// ---------------- GroupNorm finalize + gate (z already silu'd) ----------------
__global__ __launch_bounds__(256) void gn_gate_h(const f16* __restrict__ ybuf,
                                                 const f16* __restrict__ xz,
                                                 const float* __restrict__ gstats,
                                                 const float* __restrict__ gnw,
                                                 const float* __restrict__ gnb,
                                                 f16* __restrict__ g) {
    int idx = blockIdx.x * 256 + threadIdx.x;    // over M_*INNER_/8
    int c8 = (idx & (INNER_/8 - 1)) * 8;
    int m = idx >> 8;
    int bh = (m >> 11) * HEADS_ + (c8 >> 8);
    const float cnt = (float)(L_ * HDIM_);
    float mean = gstats[bh*2] / cnt;
    float var  = gstats[bh*2+1] / cnt - mean*mean;
    float rstd = rsqrtf(var + EPS_);
    size_t off = (size_t)m * INNER_ + c8;
    half8 yv = *(const half8*)&ybuf[off];
    half8 zv = *(const half8*)&xz[(size_t)m * XZS_ + INNER_ + c8];   // pre-silu'd
    float4 w0 = *(const float4*)&gnw[c8], w1 = *(const float4*)&gnw[c8+4];
    float4 b0 = *(const float4*)&gnb[c8], b1 = *(const float4*)&gnb[c8+4];
    float wv[8] = {w0.x, w0.y, w0.z, w0.w, w1.x, w1.y, w1.z, w1.w};
    float bv[8] = {b0.x, b0.y, b0.z, b0.w, b1.x, b1.y, b1.z, b1.w};
    half8 o;
#pragma unroll
    for (int j = 0; j < 8; ++j) {
        float v = ((float)yv[j] - mean) * rstd * wv[j] + bv[j];
        o[j] = (f16)(v * (float)zv[j]);
    }
    *(half8*)&g[off] = o;
}

// ---------------- launch ----------------
extern "C" void kernel_launch(void* const* d_in, const int* in_sizes, int n_in,
                              void* d_out, int out_size, void* d_ws, size_t ws_size,
                              hipStream_t stream) {
    const float* input  = (const float*)d_in[0];
    const float* Wx     = (const float*)d_in[1];
    const float* Wz     = (const float*)d_in[2];
    const float* conv_w = (const float*)d_in[3];
    const float* conv_b = (const float*)d_in[4];
    const float* Wb     = (const float*)d_in[5];
    const float* Wc     = (const float*)d_in[6];
    const float* Wdt    = (const float*)d_in[7];
    const float* b_dt   = (const float*)d_in[8];
    const float* log_a  = (const float*)d_in[9];
    const float* d_par  = (const float*)d_in[10];
    const float* gn_w   = (const float*)d_in[11];
    const float* gn_b   = (const float*)d_in[12];
    const float* Wout   = (const float*)d_in[13];
    float* out = (float*)d_out;

    float* ws = (float*)d_ws;
    size_t off = 0;
    auto alloc = [&](size_t nfloats) { float* p = ws + off; off += (nfloats + 63) & ~(size_t)63; return p; };
    f16* input_h = (f16*)alloc((size_t)M_*DIM_/2);
    f16* wxz_h   = (f16*)alloc((size_t)XZS_*DIM_/2);
    f16* wbc_h   = (f16*)alloc((size_t)BCS_*INNER_/2);
    f16* wout_h  = (f16*)alloc((size_t)DIM_*INNER_/2);
    f16* xz_h    = (f16*)alloc((size_t)M_*XZS_/2);
    f16* xconv_h = (f16*)alloc((size_t)M_*INNER_/2);
    f16* xT_h    = (f16*)alloc((size_t)M_*INNER_/2);
    f16* gbuf_h  = (f16*)alloc((size_t)M_*INNER_/2);
    f16* bcmat_h = (f16*)alloc((size_t)M_*BCS_/2);
    f16* pbuf_h  = (f16*)alloc((size_t)NCHUNK_*Q_*Q_/2);
    f16* sloc_h  = (f16*)alloc((size_t)NCHUNK_*STATE_*HDIM_/2);
    f16* ybuf_h  = (f16*)alloc((size_t)M_*INNER_/2);
    float* dtb   = alloc((size_t)M_*HEADS_);
    float* eAb   = alloc((size_t)M_*HEADS_);
    float* cdec  = alloc((size_t)NCHUNK_);
    float* gstat = alloc((size_t)2*B_*HEADS_);

    dim3 blk(256);

    cast_all<<<12288, blk, 0, stream>>>(input, Wx, Wz, Wb, Wc, Wout,
                                        input_h, wxz_h, wbc_h, wout_h);
    hgemm<128,true,true><<<dim3(XZS_/128, M_/128), blk, 0, stream>>>(input_h, wxz_h, xz_h, DIM_, XZS_);
    conv_silu_dt<<<M_, blk, 0, stream>>>(xz_h, conv_w, conv_b, Wdt, b_dt, xconv_h, dtb);
    hgemm<64,true,false><<<dim3(BCS_/64, M_/128), blk, 0, stream>>>(xconv_h, wbc_h, bcmat_h, INNER_, BCS_);
    xpose_k<<<2048, blk, 0, stream>>>(xconv_h, xT_h, gstat);
    ssd12<<<NCHUNK_, blk, 0, stream>>>(bcmat_h, dtb, log_a, d_par, xT_h, pbuf_h, sloc_h, eAb, cdec);
    chunk_scan_k<<<256, blk, 0, stream>>>(sloc_h, cdec);
    ssd_phase3<<<NCHUNK_, blk, 0, stream>>>(bcmat_h, pbuf_h, xT_h, sloc_h,
                                            eAb, (float*)ybuf_h, gstat);
    gn_gate_h<<<(M_*(INNER_/8))/256, blk, 0, stream>>>(ybuf_h, xz_h, gstat, gn_w, gn_b, gbuf_h);
    hgemm<64,false,false><<<dim3(DIM_/64, M_/128), blk, 0, stream>>>(gbuf_h, wout_h, out, INNER_, DIM_);
}

// Round 10
// 345.690 us; speedup vs baseline: 1.1102x; 1.0096x over previous
//
#include <hip/hip_runtime.h>
#include <math.h>

// ---------------- problem constants ----------------
#define DIM_   1024
#define STATE_ 64
#define HEADS_ 8
#define INNER_ 2048
#define HDIM_  256          // INNER/HEADS
#define B_     2
#define L_     2048
#define M_     (B_*L_)      // 4096 rows total
#define EPS_   1e-5f
#define Q_     64           // SSD chunk length
#define NC_    (L_/Q_)      // 32 chunks per sequence
#define NCHUNK_ (B_*HEADS_*NC_)  // 512 chunk-blocks
#define BCS_   1024         // combined B|C projection row stride
#define XZS_   4096         // combined x|z row stride

typedef _Float16 f16;
typedef __attribute__((ext_vector_type(8))) _Float16 half8;
typedef __attribute__((ext_vector_type(4))) _Float16 half4;
typedef __attribute__((ext_vector_type(4))) float    f32x4;

__device__ __forceinline__ float siluf(float x) { return x / (1.f + expf(-x)); }

__device__ __forceinline__ void gload_lds16(const void* g, void* l) {
    __builtin_amdgcn_global_load_lds((const __attribute__((address_space(1))) void*)g,
                                     (__attribute__((address_space(3))) void*)l, 16, 0, 0);
}

// ---------------- merged fp32 -> f16 cast of all operands ----------------
__global__ __launch_bounds__(256) void cast_all(const float* __restrict__ in0,
                                                const float* __restrict__ Wx,
                                                const float* __restrict__ Wz,
                                                const float* __restrict__ Wb,
                                                const float* __restrict__ Wc,
                                                const float* __restrict__ Wout,
                                                f16* __restrict__ input_h,
                                                f16* __restrict__ wxz_h,
                                                f16* __restrict__ wbc_h,
                                                f16* __restrict__ wout_h) {
    int i = blockIdx.x * 256 + threadIdx.x;
    const float* src; f16* dst; int off;
    if      (i < 1048576) { src = in0;  dst = input_h;            off = i; }
    else if (i < 1572864) { src = Wx;   dst = wxz_h;              off = i - 1048576; }
    else if (i < 2097152) { src = Wz;   dst = wxz_h + 2097152;    off = i - 1572864; }
    else if (i < 2359296) { src = Wb;   dst = wbc_h;              off = i - 2097152; }
    else if (i < 2621440) { src = Wc;   dst = wbc_h + 1048576;    off = i - 2359296; }
    else                  { src = Wout; dst = wout_h;             off = i - 2621440; }
    float4 v = *(const float4*)&src[(size_t)off * 4];
    half4 o;
    o[0] = (f16)v.x; o[1] = (f16)v.y; o[2] = (f16)v.z; o[3] = (f16)v.w;
    *(half4*)&dst[(size_t)off * 4] = o;
}

// ---------------- deep-pipelined 256x256 GEMM for xz: C = A.W^T, silu on cols>=INNER_ ----------------
// 512 threads = 8 waves (2M x 4N), per-wave 128x64 output. LDS = 4-deep ring of
// BK=32 tiles (A 256x32 | B 256x32 = 32 KB/slot, 128 KB total). One raw s_barrier
// per K-tile with counted s_waitcnt vmcnt(8) (2 K-tiles of loads stay in flight
// across the barrier -- never drained to 0). Swizzle: chunk ^= (row>>1)&3 on the
// global source col, linear LDS dest, same XOR on ds_read (involution).
__global__ __launch_bounds__(512) void hgemm8p(const f16* __restrict__ A,
                                               const f16* __restrict__ W,
                                               f16* __restrict__ Cout,
                                               int K, int N) {
    __shared__ f16 lds[65536];          // 128 KB
    const int tid = threadIdx.x;
    const int wid = tid >> 6, lane = tid & 63;
    const int wm = wid >> 2, wn = wid & 3;
    const int r = lane & 15, kg = lane >> 4;
    const int bm = blockIdx.y * 256, bn = blockIdx.x * 256;

    // staging constants: issue unit = 512 x 16B = one 128-row half of one matrix
    const int srow = tid >> 2;                               // 0..127
    const int scol = ((tid & 3) ^ ((srow >> 1) & 3)) * 8;    // pre-swizzled source col
    const f16* ga0 = A + (size_t)(bm + srow) * K + scol;
    const f16* ga1 = A + (size_t)(bm + 128 + srow) * K + scol;
    const f16* gw0 = W + (size_t)(bn + srow) * K + scol;
    const f16* gw1 = W + (size_t)(bn + 128 + srow) * K + scol;
    const int dbase = (tid & ~63) * 8;                       // wave-uniform LDS elems

    int aoff[8], boff[4];
#pragma unroll
    for (int mf = 0; mf < 8; ++mf) {
        int rr = wm * 128 + mf * 16 + r;
        aoff[mf] = rr * 32 + ((kg ^ ((rr >> 1) & 3)) << 3);
    }
#pragma unroll
    for (int nf = 0; nf < 4; ++nf) {
        int wr = wn * 64 + nf * 16 + r;
        boff[nf] = 8192 + wr * 32 + ((kg ^ ((wr >> 1) & 3)) << 3);
    }

    f32x4 acc[8][4];
#pragma unroll
    for (int mf = 0; mf < 8; ++mf)
#pragma unroll
        for (int nf = 0; nf < 4; ++nf) acc[mf][nf] = (f32x4)0.f;

    const int KT = K >> 5;

    // prologue: stage K-tiles 0,1,2 (12 issues), retire kt0 (allow 8 outstanding)
#pragma unroll
    for (int kt = 0; kt < 3; ++kt) {
        f16* base = &lds[(kt & 3) * 16384];
        int ko = kt << 5;
        gload_lds16(ga0 + ko, base + dbase);
        gload_lds16(ga1 + ko, base + 4096 + dbase);
        gload_lds16(gw0 + ko, base + 8192 + dbase);
        gload_lds16(gw1 + ko, base + 12288 + dbase);
    }
    asm volatile("s_waitcnt vmcnt(8)" ::: "memory");
    __builtin_amdgcn_s_barrier();
    asm volatile("" ::: "memory");

    for (int kt = 0; kt < KT; ++kt) {
        f16* ring = &lds[(kt & 3) * 16384];
        const bool st = (kt + 3) < KT;
        f16* sbase = &lds[((kt + 3) & 3) * 16384];     // == ring of kt-1 (consumed)
        const int sko = (kt + 3) << 5;

        if (st) {                                       // stage A halves of kt+3
            gload_lds16(ga0 + sko, sbase + dbase);
            gload_lds16(ga1 + sko, sbase + 4096 + dbase);
        }
        half8 bfr[4], afr[4];
#pragma unroll
        for (int nf = 0; nf < 4; ++nf) bfr[nf] = *(const half8*)&ring[boff[nf]];
#pragma unroll
        for (int mf = 0; mf < 4; ++mf) afr[mf] = *(const half8*)&ring[aoff[mf]];
#pragma unroll
        for (int mf = 0; mf < 4; ++mf)
#pragma unroll
            for (int nf = 0; nf < 4; ++nf)
                acc[mf][nf] = __builtin_amdgcn_mfma_f32_16x16x32_f16(afr[mf], bfr[nf], acc[mf][nf], 0, 0, 0);

        if (st) {                                       // stage B halves of kt+3
            gload_lds16(gw0 + sko, sbase + 8192 + dbase);
            gload_lds16(gw1 + sko, sbase + 12288 + dbase);
        }
#pragma unroll
        for (int mf = 0; mf < 4; ++mf) afr[mf] = *(const half8*)&ring[aoff[4 + mf]];
#pragma unroll
        for (int mf = 0; mf < 4; ++mf)
#pragma unroll
            for (int nf = 0; nf < 4; ++nf)
                acc[4 + mf][nf] = __builtin_amdgcn_mfma_f32_16x16x32_f16(afr[mf], bfr[nf], acc[4 + mf][nf], 0, 0, 0);

        if (kt + 1 < KT) {                              // K-tile boundary: counted, not drained
            asm volatile("s_waitcnt vmcnt(8)" ::: "memory");
            __builtin_amdgcn_s_barrier();
            asm volatile("" ::: "memory");
        }
    }

#pragma unroll
    for (int mf = 0; mf < 8; ++mf)
#pragma unroll
        for (int nf = 0; nf < 4; ++nf) {
            int row = bm + wm * 128 + mf * 16 + kg * 4;
            int col = bn + wn * 64 + nf * 16 + r;
#pragma unroll
            for (int j = 0; j < 4; ++j) {
                float v = acc[mf][nf][j];
                if (col >= INNER_) v = siluf(v);
                Cout[(size_t)(row + j) * N + col] = (f16)v;
            }
        }
}

// ---------------- 128xBN BK=32 GEMM (BC- and out-projections, N=1024) ----------------
template<int BN, bool OUTF16>
__global__ __launch_bounds__(256) void hgemm(const f16* __restrict__ A,
                                             const f16* __restrict__ W,
                                             void* __restrict__ Cout,
                                             int K, int N) {
    constexpr int N_FR = BN / 32;
    constexpr int NITER = (128 + BN) / 64;
    __shared__ f16 sA[128 * 32];
    __shared__ f16 sW[BN * 32];
    const int tid  = threadIdx.x;
    const int wid  = tid >> 6;
    const int lane = tid & 63;
    const int bm = blockIdx.y * 128;
    const int bn = blockIdx.x * BN;
    const int wr = wid >> 1, wc = wid & 1;
    const int r  = lane & 15, kg = lane >> 4;

    const f16* gsrc[NITER];
    f16* ldst[NITER];
#pragma unroll
    for (int i = 0; i < NITER; ++i) {
        int slot = tid + i * 256;
        if (slot < 512) {
            int row = slot >> 2;
            int kgv = ((slot & 3) ^ ((row >> 1) & 3)) * 8;
            gsrc[i] = A + (size_t)(bm + row) * K + kgv;
        } else {
            int row = (slot - 512) >> 2;
            int kgv = ((slot & 3) ^ ((row >> 1) & 3)) * 8;
            gsrc[i] = W + (size_t)(bn + row) * K + kgv;
        }
        int slot0 = (tid & ~63) + i * 256;
        ldst[i] = (slot0 < 512) ? &sA[slot0 * 8] : &sW[(slot0 - 512) * 8];
    }

    int aoff[4], boff[N_FR];
#pragma unroll
    for (int m = 0; m < 4; ++m) {
        int arow = wr * 64 + m * 16 + r;
        aoff[m] = arow * 32 + ((kg ^ ((arow >> 1) & 3)) << 3);
    }
#pragma unroll
    for (int n = 0; n < N_FR; ++n) {
        int wrow = wc * (BN / 2) + n * 16 + r;
        boff[n] = wrow * 32 + ((kg ^ ((wrow >> 1) & 3)) << 3);
    }

    f32x4 acc[4][N_FR];
#pragma unroll
    for (int m = 0; m < 4; ++m)
#pragma unroll
        for (int n = 0; n < N_FR; ++n) acc[m][n] = (f32x4)0.f;

    for (int k0 = 0; k0 < K; k0 += 32) {
#pragma unroll
        for (int i = 0; i < NITER; ++i) gload_lds16(gsrc[i] + k0, ldst[i]);
        __syncthreads();
        half8 av[4], bv[N_FR];
#pragma unroll
        for (int m = 0; m < 4; ++m) av[m] = *(const half8*)&sA[aoff[m]];
#pragma unroll
        for (int n = 0; n < N_FR; ++n) bv[n] = *(const half8*)&sW[boff[n]];
#pragma unroll
        for (int m = 0; m < 4; ++m)
#pragma unroll
            for (int n = 0; n < N_FR; ++n)
                acc[m][n] = __builtin_amdgcn_mfma_f32_16x16x32_f16(av[m], bv[n], acc[m][n], 0, 0, 0);
        __syncthreads();
    }

#pragma unroll
    for (int m = 0; m < 4; ++m)
#pragma unroll
        for (int n = 0; n < N_FR; ++n) {
            int row0o = bm + wr * 64 + m * 16 + kg * 4;
            int col   = bn + wc * (BN / 2) + n * 16 + r;
#pragma unroll
            for (int j = 0; j < 4; ++j) {
                float v = acc[m][n][j];
                if (OUTF16) ((f16*)Cout)[(size_t)(row0o + j) * N + col] = (f16)v;
                else        ((float*)Cout)[(size_t)(row0o + j) * N + col] = v;
            }
        }
}

// ---------------- causal conv (K=4) + bias + SiLU + fused dt-projection ----------------
__global__ __launch_bounds__(256) void conv_silu_dt(const f16* __restrict__ xz,
                                                    const float* __restrict__ cw,
                                                    const float* __restrict__ cb,
                                                    const float* __restrict__ Wdt,
                                                    const float* __restrict__ bdt,
                                                    f16* __restrict__ xc,
                                                    float* __restrict__ dtb) {
    __shared__ float sred[4][HEADS_];
    const int m = blockIdx.x;
    const int tid = threadIdx.x;
    const int c8 = tid * 8;
    const int t = m & (L_ - 1);
    float acc[8];
    float4 wv[8];
#pragma unroll
    for (int j = 0; j < 8; ++j) { acc[j] = cb[c8 + j]; wv[j] = *(const float4*)&cw[(c8 + j) * 4]; }
#pragma unroll
    for (int k = 0; k < 4; ++k) {
        int tt = t - 3 + k;
        if (tt >= 0) {
            half8 xv = *(const half8*)&xz[(size_t)(m - 3 + k) * XZS_ + c8];
#pragma unroll
            for (int j = 0; j < 8; ++j) acc[j] += (float)xv[j] * ((const float*)&wv[j])[k];
        }
    }
    float xf[8];
    half8 o;
#pragma unroll
    for (int j = 0; j < 8; ++j) { xf[j] = siluf(acc[j]); o[j] = (f16)xf[j]; }
    *(half8*)&xc[(size_t)m * INNER_ + c8] = o;

    float p[HEADS_];
#pragma unroll
    for (int h = 0; h < HEADS_; ++h) {
        float4 w0 = *(const float4*)&Wdt[h * INNER_ + c8];
        float4 w1 = *(const float4*)&Wdt[h * INNER_ + c8 + 4];
        p[h] = xf[0]*w0.x + xf[1]*w0.y + xf[2]*w0.z + xf[3]*w0.w
             + xf[4]*w1.x + xf[5]*w1.y + xf[6]*w1.z + xf[7]*w1.w;
    }
#pragma unroll
    for (int h = 0; h < HEADS_; ++h)
#pragma unroll
        for (int off = 32; off > 0; off >>= 1)
            p[h] += __shfl_down(p[h], off, 64);
    if ((tid & 63) == 0) {
#pragma unroll
        for (int h = 0; h < HEADS_; ++h) sred[tid >> 6][h] = p[h];
    }
    __syncthreads();
    if (tid < 32) {
        float v = sred[tid >> 3][tid & 7];
        v += __shfl_down(v, 16, 32);
        v += __shfl_down(v, 8, 32);
        if (tid < 8) {
            float s = v + bdt[tid];
            dtb[(size_t)m * HEADS_ + tid] = (s > 20.f) ? s : log1pf(expf(s));
        }
    }
}

// ---------------- per-head transpose + gstat zero ----------------
__global__ __launch_bounds__(256) void xpose_k(const f16* __restrict__ xc,
                                               f16* __restrict__ xT,
                                               float* __restrict__ gstat) {
    __shared__ f16 sT[64][72];
    const int blk = blockIdx.x;
    const int bh = blk >> 7;
    const int rem = blk & 127;
    const int tt = rem >> 2;
    const int pt = rem & 3;
    const int b = bh >> 3, h = bh & 7;
    const int tid = threadIdx.x;
    if (blk == 0 && tid < 2 * B_ * HEADS_) gstat[tid] = 0.f;
#pragma unroll
    for (int it = 0; it < 2; ++it) {
        int q = tid + it * 256;
        int tr = q >> 3;
        int p0 = (q & 7) * 8;
        half8 v = *(const half8*)&xc[(size_t)(b * L_ + tt * 64 + tr) * INNER_ + h * HDIM_ + pt * 64 + p0];
        *(half8*)&sT[tr][p0] = v;
    }
    __syncthreads();
#pragma unroll
    for (int it = 0; it < 2; ++it) {
        int q = tid + it * 256;
        int pr = q >> 3;
        int t0 = (q & 7) * 8;
        half8 v;
#pragma unroll
        for (int j = 0; j < 8; ++j) v[j] = sT[t0 + j][pr];
        *(half8*)&xT[((size_t)bh * HDIM_ + pt * 64 + pr) * L_ + tt * 64 + t0] = v;
    }
}

// ---------------- fused SSD: prefix scan + P=mask(C.B^T)+d*I + S^T = X^T.(wB) ----------------
__global__ __launch_bounds__(256) void ssd12(const f16* __restrict__ bc,
                                             const float* __restrict__ dtb,
                                             const float* __restrict__ log_a,
                                             const float* __restrict__ dparam,
                                             const f16* __restrict__ xT,
                                             f16* __restrict__ pbuf,
                                             f16* __restrict__ sloc,
                                             float* __restrict__ eAbuf,
                                             float* __restrict__ cdecay) {
    __shared__ float sA[Q_], sDt[Q_], sw[Q_];
    __shared__ f16 sB[Q_ * Q_];
    const int tid = threadIdx.x;
    const int chunk = blockIdx.x;
    const int bh = chunk / NC_;
    const int ck = chunk - bh * NC_;
    const int b = bh >> 3, h = bh & 7;
    const int m0 = b * L_ + ck * Q_;

    const int s0 = tid >> 3,        n00 = (tid & 7) * 8;
    const int s1 = (tid + 256) >> 3, n01 = (tid & 7) * 8;
    half8 bv0 = *(const half8*)&bc[(size_t)(m0 + s0) * BCS_ + h * STATE_ + n00];
    half8 bv1 = *(const half8*)&bc[(size_t)(m0 + s1) * BCS_ + h * STATE_ + n01];

    if (tid < 64) {
        float dt = dtb[(size_t)(m0 + tid) * HEADS_ + h];
        float a = -expf(log_a[h]);
        float x = dt * a;
#pragma unroll
        for (int off = 1; off < 64; off <<= 1) {
            float v = __shfl_up(x, off, 64);
            if (tid >= off) x += v;
        }
        float Alast = __shfl(x, 63, 64);
        sA[tid] = x;
        sDt[tid] = dt;
        sw[tid] = expf(Alast - x) * dt;
        eAbuf[(size_t)(m0 + tid) * HEADS_ + h] = expf(x);
        if (tid == 0) cdecay[chunk] = expf(Alast);
    }
    __syncthreads();

    {
        float w0 = sw[s0], w1 = sw[s1];
        half8 o0, o1;
#pragma unroll
        for (int j = 0; j < 8; ++j) { o0[j] = (f16)((float)bv0[j] * w0); o1[j] = (f16)((float)bv1[j] * w1); }
        *(half8*)&sB[s0 * Q_ + (n00 ^ ((s0 & 7) << 3))] = o0;
        *(half8*)&sB[s1 * Q_ + (n01 ^ ((s1 & 7) << 3))] = o1;
    }

    const int w = tid >> 6, lane = tid & 63;
    const int r = lane & 15, kg = lane >> 4;

    {
        const float dpar = dparam[h];
        const int ft = w;
        const f16* Crow = bc + (size_t)(m0 + ft * 16 + r) * BCS_ + 512 + h * STATE_;
        half8 a0 = *(const half8*)(Crow + kg * 8);
        half8 a1 = *(const half8*)(Crow + 32 + kg * 8);
#pragma unroll
        for (int fs = 0; fs < 4; ++fs) {
            const f16* Brow = bc + (size_t)(m0 + fs * 16 + r) * BCS_ + h * STATE_;
            half8 b0 = *(const half8*)(Brow + kg * 8);
            half8 b1 = *(const half8*)(Brow + 32 + kg * 8);
            f32x4 g = (f32x4)0.f;
            g = __builtin_amdgcn_mfma_f32_16x16x32_f16(a0, b0, g, 0, 0, 0);
            g = __builtin_amdgcn_mfma_f32_16x16x32_f16(a1, b1, g, 0, 0, 0);
            int s = fs * 16 + r;
            float As = sA[s], dts = sDt[s];
#pragma unroll
            for (int j = 0; j < 4; ++j) {
                int t = ft * 16 + kg * 4 + j;
                float val = (t >= s) ? g[j] * expf(sA[t] - As) * dts : 0.f;
                if (t == s) val += dpar;
                pbuf[((size_t)chunk * Q_ + t) * Q_ + s] = (f16)val;
            }
        }
    }
    __syncthreads();

    f32x4 acc[4][4];
#pragma unroll
    for (int i = 0; i < 4; ++i)
#pragma unroll
        for (int j = 0; j < 4; ++j) acc[i][j] = (f32x4)0.f;

#pragma unroll
    for (int kk = 0; kk < 2; ++kk) {
        half8 a[4], bfr[4];
#pragma unroll
        for (int pf = 0; pf < 4; ++pf) {
            int p = w * 64 + pf * 16 + r;
            a[pf] = *(const half8*)&xT[((size_t)bh * HDIM_ + p) * L_ + ck * Q_ + kk * 32 + kg * 8];
        }
#pragma unroll
        for (int nf = 0; nf < 4; ++nf) {
            int n = nf * 16 + r;
            half8 v;
#pragma unroll
            for (int j = 0; j < 8; ++j) {
                int s = kk * 32 + kg * 8 + j;
                v[j] = sB[s * Q_ + (n ^ (j << 3))];
            }
            bfr[nf] = v;
        }
#pragma unroll
        for (int pf = 0; pf < 4; ++pf)
#pragma unroll
            for (int nf = 0; nf < 4; ++nf)
                acc[pf][nf] = __builtin_amdgcn_mfma_f32_16x16x32_f16(a[pf], bfr[nf], acc[pf][nf], 0, 0, 0);
    }
#pragma unroll
    for (int pf = 0; pf < 4; ++pf)
#pragma unroll
        for (int nf = 0; nf < 4; ++nf) {
            int n = nf * 16 + r;
#pragma unroll
            for (int j = 0; j < 4; ++j) {
                int p = w * 64 + pf * 16 + kg * 4 + j;
                sloc[((size_t)chunk * HDIM_ + p) * STATE_ + n] = (f16)acc[pf][nf][j];
            }
        }
}

// ---------------- SSD phase B: sequential inter-chunk state recurrence (half4) ----------------
__global__ __launch_bounds__(256) void chunk_scan_k(f16* __restrict__ sloc,
                                                    const float* __restrict__ cdecay) {
    int bh = blockIdx.x >> 4;
    int el4 = (((blockIdx.x & 15) * 256 + threadIdx.x) << 2);
    float s0 = 0.f, s1 = 0.f, s2 = 0.f, s3 = 0.f;
    for (int c = 0; c < NC_; ++c) {
        size_t chunk = (size_t)bh * NC_ + c;
        f16* ptr = sloc + chunk * (size_t)(STATE_ * HDIM_) + el4;
        half4 v = *(const half4*)ptr;
        half4 o; o[0] = (f16)s0; o[1] = (f16)s1; o[2] = (f16)s2; o[3] = (f16)s3;
        *(half4*)ptr = o;
        float d = cdecay[chunk];
        s0 = d * s0 + (float)v[0];
        s1 = d * s1 + (float)v[1];
        s2 = d * s2 + (float)v[2];
        s3 = d * s3 + (float)v[3];
    }
}

// ---------------- SSD phase 3 (MFMA): Y = [P | eA*C].[X^T | S_in^T]^T ; GN stats ----------------
__global__ __launch_bounds__(256) void ssd_phase3(const f16* __restrict__ bc,
                                                  const f16* __restrict__ pbuf,
                                                  const f16* __restrict__ xT,
                                                  const f16* __restrict__ sloc,
                                                  const float* __restrict__ eAbuf,
                                                  float* __restrict__ ybuf16_,
                                                  float* __restrict__ gstats) {
    f16* ybuf = (f16*)ybuf16_;
    __shared__ float red[512];
    const int tid = threadIdx.x;
    const int chunk = blockIdx.x;
    const int bh = chunk / NC_;
    const int ck = chunk - bh * NC_;
    const int b = bh >> 3, h = bh & 7;
    const int m0 = b * L_ + ck * Q_;
    const int w = tid >> 6, lane = tid & 63;
    const int r = lane & 15, kg = lane >> 4;

    float eA[4];
#pragma unroll
    for (int ft = 0; ft < 4; ++ft)
        eA[ft] = eAbuf[(size_t)(m0 + ft * 16 + r) * HEADS_ + h];

    f32x4 acc[4][4];
#pragma unroll
    for (int i = 0; i < 4; ++i)
#pragma unroll
        for (int j = 0; j < 4; ++j) acc[i][j] = (f32x4)0.f;

#pragma unroll
    for (int ks = 0; ks < 4; ++ks) {
        half8 a[4], bfr[4];
#pragma unroll
        for (int ft = 0; ft < 4; ++ft) {
            int t = ft * 16 + r;
            if (ks < 2) {
                a[ft] = *(const half8*)&pbuf[((size_t)chunk * Q_ + t) * Q_ + ks * 32 + kg * 8];
            } else {
                half8 c = *(const half8*)&bc[(size_t)(m0 + t) * BCS_ + 512 + h * STATE_ + (ks - 2) * 32 + kg * 8];
                half8 sc;
#pragma unroll
                for (int j = 0; j < 8; ++j) sc[j] = (f16)(eA[ft] * (float)c[j]);
                a[ft] = sc;
            }
        }
#pragma unroll
        for (int pf = 0; pf < 4; ++pf) {
            int p = w * 64 + pf * 16 + r;
            if (ks < 2)
                bfr[pf] = *(const half8*)&xT[((size_t)bh * HDIM_ + p) * L_ + ck * Q_ + ks * 32 + kg * 8];
            else
                bfr[pf] = *(const half8*)&sloc[((size_t)chunk * HDIM_ + p) * STATE_ + (ks - 2) * 32 + kg * 8];
        }
#pragma unroll
        for (int ft = 0; ft < 4; ++ft)
#pragma unroll
            for (int pf = 0; pf < 4; ++pf)
                acc[ft][pf] = __builtin_amdgcn_mfma_f32_16x16x32_f16(a[ft], bfr[pf], acc[ft][pf], 0, 0, 0);
    }

    float lsum = 0.f, lsq = 0.f;
#pragma unroll
    for (int ft = 0; ft < 4; ++ft)
#pragma unroll
        for (int pf = 0; pf < 4; ++pf) {
            int p = w * 64 + pf * 16 + r;
#pragma unroll
            for (int j = 0; j < 4; ++j) {
                int t = ft * 16 + kg * 4 + j;
                size_t off = (size_t)(m0 + t) * INNER_ + h * HDIM_ + p;
                float y = acc[ft][pf][j];
                ybuf[off] = (f16)y;
                lsum += y; lsq += y * y;
            }
        }
    __syncthreads();
    red[tid] = lsum; red[256 + tid] = lsq;
    __syncthreads();
    for (int st = 128; st > 0; st >>= 1) {
        if (tid < st) { red[tid] += red[tid + st]; red[256 + tid] += red[256 + tid + st]; }
        __syncthreads();
    }
    if (tid == 0) {
        atomicAdd(&gstats[bh * 2 + 0], red[0]);
        atomicAdd(&gstats[bh * 2 + 1], red[256]);
    }
}

// ---------------- GroupNorm finalize + gate (z already silu'd) ----------------
__global__ __launch_bounds__(256) void gn_gate_h(const f16* __restrict__ ybuf,
                                                 const f16* __restrict__ xz,
                                                 const float* __restrict__ gstats,
                                                 const float* __restrict__ gnw,
                                                 const float* __restrict__ gnb,
                                                 f16* __restrict__ g) {
    int idx = blockIdx.x * 256 + threadIdx.x;
    int c8 = (idx & (INNER_/8 - 1)) * 8;
    int m = idx >> 8;
    int bh = (m >> 11) * HEADS_ + (c8 >> 8);
    const float cnt = (float)(L_ * HDIM_);
    float mean = gstats[bh*2] / cnt;
    float var  = gstats[bh*2+1] / cnt - mean*mean;
    float rstd = rsqrtf(var + EPS_);
    size_t off = (size_t)m * INNER_ + c8;
    half8 yv = *(const half8*)&ybuf[off];
    half8 zv = *(const half8*)&xz[(size_t)m * XZS_ + INNER_ + c8];
    float4 w0 = *(const float4*)&gnw[c8], w1 = *(const float4*)&gnw[c8+4];
    float4 b0 = *(const float4*)&gnb[c8], b1 = *(const float4*)&gnb[c8+4];
    float wv[8] = {w0.x, w0.y, w0.z, w0.w, w1.x, w1.y, w1.z, w1.w};
    float bv[8] = {b0.x, b0.y, b0.z, b0.w, b1.x, b1.y, b1.z, b1.w};
    half8 o;
#pragma unroll
    for (int j = 0; j < 8; ++j) {
        float v = ((float)yv[j] - mean) * rstd * wv[j] + bv[j];
        o[j] = (f16)(v * (float)zv[j]);
    }
    *(half8*)&g[off] = o;
}

// ---------------- launch ----------------
extern "C" void kernel_launch(void* const* d_in, const int* in_sizes, int n_in,
                              void* d_out, int out_size, void* d_ws, size_t ws_size,
                              hipStream_t stream) {
    const float* input  = (const float*)d_in[0];
    const float* Wx     = (const float*)d_in[1];
    const float* Wz     = (const float*)d_in[2];
    const float* conv_w = (const float*)d_in[3];
    const float* conv_b = (const float*)d_in[4];
    const float* Wb     = (const float*)d_in[5];
    const float* Wc     = (const float*)d_in[6];
    const float* Wdt    = (const float*)d_in[7];
    const float* b_dt   = (const float*)d_in[8];
    const float* log_a  = (const float*)d_in[9];
    const float* d_par  = (const float*)d_in[10];
    const float* gn_w   = (const float*)d_in[11];
    const float* gn_b   = (const float*)d_in[12];
    const float* Wout   = (const float*)d_in[13];
    float* out = (float*)d_out;

    float* ws = (float*)d_ws;
    size_t off = 0;
    auto alloc = [&](size_t nfloats) { float* p = ws + off; off += (nfloats + 63) & ~(size_t)63; return p; };
    f16* input_h = (f16*)alloc((size_t)M_*DIM_/2);
    f16* wxz_h   = (f16*)alloc((size_t)XZS_*DIM_/2);
    f16* wbc_h   = (f16*)alloc((size_t)BCS_*INNER_/2);
    f16* wout_h  = (f16*)alloc((size_t)DIM_*INNER_/2);
    f16* xz_h    = (f16*)alloc((size_t)M_*XZS_/2);
    f16* xconv_h = (f16*)alloc((size_t)M_*INNER_/2);
    f16* xT_h    = (f16*)alloc((size_t)M_*INNER_/2);
    f16* gbuf_h  = (f16*)alloc((size_t)M_*INNER_/2);
    f16* bcmat_h = (f16*)alloc((size_t)M_*BCS_/2);
    f16* pbuf_h  = (f16*)alloc((size_t)NCHUNK_*Q_*Q_/2);
    f16* sloc_h  = (f16*)alloc((size_t)NCHUNK_*STATE_*HDIM_/2);
    f16* ybuf_h  = (f16*)alloc((size_t)M_*INNER_/2);
    float* dtb   = alloc((size_t)M_*HEADS_);
    float* eAb   = alloc((size_t)M_*HEADS_);
    float* cdec  = alloc((size_t)NCHUNK_);
    float* gstat = alloc((size_t)2*B_*HEADS_);

    dim3 blk(256);

    cast_all<<<12288, blk, 0, stream>>>(input, Wx, Wz, Wb, Wc, Wout,
                                        input_h, wxz_h, wbc_h, wout_h);
    hgemm8p<<<dim3(XZS_/256, M_/256), dim3(512), 0, stream>>>(input_h, wxz_h, xz_h, DIM_, XZS_);
    conv_silu_dt<<<M_, blk, 0, stream>>>(xz_h, conv_w, conv_b, Wdt, b_dt, xconv_h, dtb);
    hgemm<64,true><<<dim3(BCS_/64, M_/128), blk, 0, stream>>>(xconv_h, wbc_h, bcmat_h, INNER_, BCS_);
    xpose_k<<<2048, blk, 0, stream>>>(xconv_h, xT_h, gstat);
    ssd12<<<NCHUNK_, blk, 0, stream>>>(bcmat_h, dtb, log_a, d_par, xT_h, pbuf_h, sloc_h, eAb, cdec);
    chunk_scan_k<<<256, blk, 0, stream>>>(sloc_h, cdec);
    ssd_phase3<<<NCHUNK_, blk, 0, stream>>>(bcmat_h, pbuf_h, xT_h, sloc_h,
                                            eAb, (float*)ybuf_h, gstat);
    gn_gate_h<<<(M_*(INNER_/8))/256, blk, 0, stream>>>(ybuf_h, xz_h, gstat, gn_w, gn_b, gbuf_h);
    hgemm<64,false><<<dim3(DIM_/64, M_/128), blk, 0, stream>>>(gbuf_h, wout_h, out, INNER_, DIM_);
}